// Round 4
// baseline (4448.981 us; speedup 1.0000x reference)
//
#include <hip/hip_runtime.h>
#include <hip/hip_bf16.h>

#define DI __device__ __forceinline__

// ---------- bf16 helpers (raw ushort bits) ----------
DI float b2f(unsigned short u) {
    union { unsigned int i; float f; } x; x.i = ((unsigned int)u) << 16; return x.f;
}
DI unsigned short f2b(float f) {
    union { float f; unsigned int i; } x; x.f = f;
    unsigned int r = x.i + 0x7fff + ((x.i >> 16) & 1);  // RNE
    return (unsigned short)(r >> 16);
}
// flavor-aware input load: f32!=0 -> fp32 array, else bf16 array
DI float ldin(const void* p, long i, int f32) {
    return f32 ? ((const float*)p)[i] : b2f(((const unsigned short*)p)[i]);
}
DI float ldval(const float* p) { return *p; }
DI float ldval(const unsigned short* p) { return b2f(*p); }
DI void stval(float* p, float v) { *p = v; }
DI void stval(unsigned short* p, float v) { *p = f2b(v); }

// ---------- constants ----------
static constexpr int N1 = 30000, N2 = 15000, R = 5;
static constexpr int IN = 128, HC0 = 256, C1 = 40;
static constexpr int CH = 1875;            // layer-0 node chunk: 16 chunks
static constexpr float NEGBIG = -1e30f;    // finite "-inf" (NaN-proof masking)

// ---------- dtype flavor detection ----------
// fp32 data read as bf16 exposes low-mantissa halves: random exponents -> huge/NaN
// values with p~0.45 each. 256 probes: P(misclassify) < 1e-40. bf16 data (N(0,0.05))
// is always small and finite.
__global__ void detect_k(const void* emb, int* flag)
{
    int lane = threadIdx.x;   // 64 threads
    int bad = 0;
    for (int j = 0; j < 4; ++j) {
        float f = b2f(((const unsigned short*)emb)[lane * 4 + j]);
        if (!(fabsf(f) < 1e8f)) bad = 1;   // catches NaN too
    }
    unsigned long long anybad = __ballot(bad != 0);
    if (lane == 0) *flag = (anybad != 0ull) ? 1 : 0;
}

// ---------- gather x[:N1] = bf16(emb[lidx[n_id[n]]]) ----------
__global__ __launch_bounds__(256) void gather_k(
    const int* __restrict__ n_id, const int* __restrict__ lidx,
    const void* __restrict__ emb, unsigned short* __restrict__ x, int rows,
    const int* __restrict__ dflag)
{
    const int f32 = *dflag;
    long t = (long)blockIdx.x * 256 + threadIdx.x;
    long n = t >> 7, d = t & 127;         // one thread per element
    if (n >= rows) return;
    long row = lidx[n_id[n]];
    x[n * IN + d] = f2b(ldin(emb, row * IN + d, f32));
}

// ---------- generic fp32-accumulate GEMM: C[b] = A[b] @ B_input[b] (+ bias_input) ----------
// A: internal ws buffer (float or bf16, compile-time). B/bias: flavor-detected inputs.
template <typename AT, typename OT>
__global__ __launch_bounds__(256) void gemm_k(
    const AT* __restrict__ A, const void* __restrict__ B,
    OT* __restrict__ C, const void* __restrict__ bias,
    const int* __restrict__ dflag,
    int M, int N, int K, long sA, long sB, long sC)
{
    __shared__ float As[16][65];
    __shared__ float Bs[16][65];
    const int f32 = *dflag;
    const int bz = blockIdx.z;
    A += (long)bz * sA; C += (long)bz * sC;
    const long boff = (long)bz * sB;
    const int tid = threadIdx.x;
    const int tx = tid & 15, ty = tid >> 4;
    const int m0 = blockIdx.y * 64, n0 = blockIdx.x * 64;
    float acc[4][4] = {};
    for (int k0 = 0; k0 < K; k0 += 16) {
        {
            const int kk = tid & 15, mm = tid >> 4;
#pragma unroll
            for (int j = 0; j < 4; ++j) {
                int m = m0 + mm + 16 * j, k = k0 + kk;
                As[kk][mm + 16 * j] = (m < M && k < K) ? ldval(&A[(long)m * K + k]) : 0.f;
            }
        }
        {
            const int nn = tid & 63, kq = tid >> 6;
#pragma unroll
            for (int j = 0; j < 4; ++j) {
                int k = k0 + kq + 4 * j, n = n0 + nn;
                Bs[kq + 4 * j][nn] = (k < K && n < N) ? ldin(B, boff + (long)k * N + n, f32) : 0.f;
            }
        }
        __syncthreads();
#pragma unroll
        for (int kk = 0; kk < 16; ++kk) {
            float av[4], bv[4];
#pragma unroll
            for (int i = 0; i < 4; ++i) av[i] = As[kk][ty + 16 * i];
#pragma unroll
            for (int j = 0; j < 4; ++j) bv[j] = Bs[kk][tx + 16 * j];
#pragma unroll
            for (int i = 0; i < 4; ++i)
#pragma unroll
                for (int j = 0; j < 4; ++j) acc[i][j] += av[i] * bv[j];
        }
        __syncthreads();
    }
#pragma unroll
    for (int i = 0; i < 4; ++i) {
        const int m = m0 + ty + 16 * i;
        if (m >= M) continue;
#pragma unroll
        for (int j = 0; j < 4; ++j) {
            const int n = n0 + tx + 16 * j;
            if (n >= N) continue;
            float v = acc[i][j];
            if (bias) v += ldin(bias, n, f32);
            stval(&C[(long)m * N + n], v);
        }
    }
}

// ---------- chunked edge pass: one wave per edge; process only tgt in [n0,n0+NC) ----------
// z_c[(r, tgt-n0)] += exp(alpha)*xj ; den_c += exp(alpha). No max-subtraction needed
// (alpha magnitudes << 1; softmax is shift-invariant).
template <int H, int C, int NC>
__global__ __launch_bounds__(256) void edge_scatter_k(
    const int* __restrict__ ei, const int* __restrict__ etype, int E, int n0,
    const unsigned short* __restrict__ hj, const unsigned short* __restrict__ hi,
    const void* __restrict__ attj, const void* __restrict__ atti,
    float* __restrict__ z, float* __restrict__ den,
    const int* __restrict__ dflag)
{
    constexpr int HC = H * C;
    constexpr int EPL = (HC + 63) / 64;              // 4 for 256, 1 for 40
    constexpr int GROUP = (H == 1) ? 64 : (C / EPL); // 16 for H=4, 64 for H=1
    const int f32 = *dflag;
    int e = (int)((blockIdx.x * 256u + threadIdx.x) >> 6);
    int lane = threadIdx.x & 63;
    if (e >= E) return;
    int tgt = ei[E + e];                  // wave-uniform -> uniform early-out
    int tl = tgt - n0;
    if (tl < 0 || tl >= NC) return;
    int src = ei[e], r = etype[e];
    int d0 = lane * EPL;
    float xj[EPL];
    float partial = 0.f;
    if constexpr (EPL == 4) {
        ushort4 xjv = *(const ushort4*)(hj + (long)src * HC + d0);
        ushort4 xiv = *(const ushort4*)(hi + (long)tgt * HC + d0);
        xj[0] = b2f(xjv.x); xj[1] = b2f(xjv.y); xj[2] = b2f(xjv.z); xj[3] = b2f(xjv.w);
        float xi0 = b2f(xiv.x), xi1 = b2f(xiv.y), xi2 = b2f(xiv.z), xi3 = b2f(xiv.w);
        long ab = (long)r * HC + d0;
        partial = ldin(attj, ab + 0, f32) * xj[0] + ldin(attj, ab + 1, f32) * xj[1]
                + ldin(attj, ab + 2, f32) * xj[2] + ldin(attj, ab + 3, f32) * xj[3]
                + ldin(atti, ab + 0, f32) * xi0 + ldin(atti, ab + 1, f32) * xi1
                + ldin(atti, ab + 2, f32) * xi2 + ldin(atti, ab + 3, f32) * xi3;
    } else {
        bool act = d0 < HC;
        float xjv = act ? b2f(hj[(long)src * HC + d0]) : 0.f;
        float xiv = act ? b2f(hi[(long)tgt * HC + d0]) : 0.f;
        float aj  = act ? ldin(attj, (long)r * HC + d0, f32) : 0.f;
        float ai  = act ? ldin(atti, (long)r * HC + d0, f32) : 0.f;
        xj[0] = xjv;
        partial = aj * xjv + ai * xiv;
    }
#pragma unroll
    for (int m = 1; m < GROUP; m <<= 1) partial += __shfl_xor(partial, m, 64);
    float a = partial > 0.f ? partial : 0.2f * partial;   // leaky_relu 0.2
    a = fminf(a, 60.f);                                   // defensive: no inf from expf
    float ex = expf(a);
    int h = (H == 1) ? 0 : (lane / GROUP);
    long segbase = (long)r * NC + tl;
    if ((lane & (GROUP - 1)) == 0) atomicAdd(&den[segbase * H + h], ex);
    if (d0 < HC) {
#pragma unroll
        for (int j = 0; j < EPL; ++j) atomicAdd(&z[segbase * HC + d0 + j], ex * xj[j]);
    }
}

// ---------- z /= max(den, 1e-16), float4 per thread ----------
template <int H, int C>
__global__ __launch_bounds__(256) void norm_z_k(
    float* __restrict__ z, const float* __restrict__ den, long nvec4)
{
    constexpr int HC = H * C;
    long t = (long)blockIdx.x * 256 + threadIdx.x;
    if (t >= nvec4) return;
    long base = t * 4;
    long rn = base / HC;
    int d = (int)(base % HC);
    int h = d / C;
    float inv = 1.f / fmaxf(den[rn * H + h], 1e-16f);
    float4* z4 = (float4*)z;
    float4 v = z4[t];
    v.x *= inv; v.y *= inv; v.z *= inv; v.w *= inv;
    z4[t] = v;
}

// ---------- fused relation attention, layer 0 (H=4,C=64): one wave per node ----------
// q/k/v are [R][CH][256] bf16 chunk slices. x1 bf16 RMW: self -> relu(self + attn).
__global__ __launch_bounds__(256) void fused_attn0_k(
    const unsigned short* __restrict__ qb, const unsigned short* __restrict__ kb,
    const unsigned short* __restrict__ vb, const void* __restrict__ wrel,
    unsigned short* __restrict__ x1, int n0, int nloc,
    const int* __restrict__ dflag)
{
    const int f32 = *dflag;
    int nl = (int)((blockIdx.x * 256u + threadIdx.x) >> 6);
    int lane = threadIdx.x & 63;
    if (nl >= nloc) return;
    int n = n0 + nl;
    int dd = ((lane >> 4) << 6) + ((lane & 15) << 2);
    float qf[5][4], kf[5][4];
#pragma unroll
    for (int r = 0; r < 5; ++r) {
        ushort4 qv = *(const ushort4*)(qb + ((long)r * CH + nl) * 256 + dd);
        ushort4 kv = *(const ushort4*)(kb + ((long)r * CH + nl) * 256 + dd);
        qf[r][0] = b2f(qv.x); qf[r][1] = b2f(qv.y); qf[r][2] = b2f(qv.z); qf[r][3] = b2f(qv.w);
        kf[r][0] = b2f(kv.x); kf[r][1] = b2f(kv.y); kf[r][2] = b2f(kv.z); kf[r][3] = b2f(kv.w);
    }
    float psi[5][5];
#pragma unroll
    for (int r = 0; r < 5; ++r)
#pragma unroll
        for (int s = 0; s < 5; ++s) {
            float p = qf[r][0] * kf[s][0] + qf[r][1] * kf[s][1] +
                      qf[r][2] * kf[s][2] + qf[r][3] * kf[s][3];
            p += __shfl_xor(p, 1, 64); p += __shfl_xor(p, 2, 64);
            p += __shfl_xor(p, 4, 64); p += __shfl_xor(p, 8, 64);
            psi[r][s] = p;   // per-head dot, replicated across the 16-lane group
        }
    float pw[5] = {0.f, 0.f, 0.f, 0.f, 0.f};
#pragma unroll
    for (int r = 0; r < 5; ++r) {
        float rowsum = psi[r][0] + psi[r][1] + psi[r][2] + psi[r][3] + psi[r][4];
        float vals[5], m = NEGBIG;
#pragma unroll
        for (int s = 0; s < 5; ++s) {
            float v = (psi[r][s] == 0.f && rowsum != 0.f) ? NEGBIG : psi[r][s];
            vals[s] = v; m = fmaxf(m, v);
        }
        float es[5], sum = 0.f;
#pragma unroll
        for (int s = 0; s < 5; ++s) { es[s] = expf(vals[s] - m); sum += es[s]; }
        float wr = ldin(wrel, r, f32) / sum;   // sum >= 1 always
#pragma unroll
        for (int s = 0; s < 5; ++s) pw[s] += wr * es[s];
    }
    float acc[4] = {0.f, 0.f, 0.f, 0.f};
#pragma unroll
    for (int s = 0; s < 5; ++s) {
        ushort4 vv = *(const ushort4*)(vb + ((long)s * CH + nl) * 256 + dd);
        acc[0] += pw[s] * b2f(vv.x); acc[1] += pw[s] * b2f(vv.y);
        acc[2] += pw[s] * b2f(vv.z); acc[3] += pw[s] * b2f(vv.w);
    }
    ushort4* xp = (ushort4*)(x1 + (long)n * 256 + dd);
    ushort4 sv = *xp;
    sv.x = f2b(fmaxf(b2f(sv.x) + acc[0], 0.f));
    sv.y = f2b(fmaxf(b2f(sv.y) + acc[1], 0.f));
    sv.z = f2b(fmaxf(b2f(sv.z) + acc[2], 0.f));
    sv.w = f2b(fmaxf(b2f(sv.w) + acc[3], 0.f));
    *xp = sv;
}

// ---------- fused relation attention, layer 1 (H=1,C=40) + log_softmax -> d_out ----------
__global__ __launch_bounds__(256) void fused_attn1_k(
    const unsigned short* __restrict__ qb, const unsigned short* __restrict__ kb,
    const unsigned short* __restrict__ vb, const void* __restrict__ wrel,
    const float* __restrict__ self1, void* __restrict__ out, int N,
    const int* __restrict__ dflag)
{
    const int f32 = *dflag;
    int n = (int)((blockIdx.x * 256u + threadIdx.x) >> 6);
    int lane = threadIdx.x & 63;
    if (n >= N) return;
    bool act = lane < 40;
    float qf[5], kf[5];
#pragma unroll
    for (int r = 0; r < 5; ++r) {
        long o = ((long)r * N + n) * 40 + lane;
        qf[r] = act ? b2f(qb[o]) : 0.f;
        kf[r] = act ? b2f(kb[o]) : 0.f;
    }
    float psi[5][5];
#pragma unroll
    for (int r = 0; r < 5; ++r)
#pragma unroll
        for (int s = 0; s < 5; ++s) {
            float p = qf[r] * kf[s];
            p += __shfl_xor(p, 1, 64);  p += __shfl_xor(p, 2, 64);
            p += __shfl_xor(p, 4, 64);  p += __shfl_xor(p, 8, 64);
            p += __shfl_xor(p, 16, 64); p += __shfl_xor(p, 32, 64);
            psi[r][s] = p;
        }
    float pw[5] = {0.f, 0.f, 0.f, 0.f, 0.f};
#pragma unroll
    for (int r = 0; r < 5; ++r) {
        float rowsum = psi[r][0] + psi[r][1] + psi[r][2] + psi[r][3] + psi[r][4];
        float vals[5], m = NEGBIG;
#pragma unroll
        for (int s = 0; s < 5; ++s) {
            float v = (psi[r][s] == 0.f && rowsum != 0.f) ? NEGBIG : psi[r][s];
            vals[s] = v; m = fmaxf(m, v);
        }
        float es[5], sum = 0.f;
#pragma unroll
        for (int s = 0; s < 5; ++s) { es[s] = expf(vals[s] - m); sum += es[s]; }
        float wr = ldin(wrel, r, f32) / sum;
#pragma unroll
        for (int s = 0; s < 5; ++s) pw[s] += wr * es[s];
    }
    float val = NEGBIG;
    if (act) {
        float acc = 0.f;
#pragma unroll
        for (int s = 0; s < 5; ++s) acc += pw[s] * b2f(vb[((long)s * N + n) * 40 + lane]);
        val = self1[(long)n * 40 + lane] + acc;
    }
    float m = val;
#pragma unroll
    for (int msk = 1; msk < 64; msk <<= 1) m = fmaxf(m, __shfl_xor(m, msk, 64));
    float e = act ? expf(val - m) : 0.f;   // val-m <= 0 -> e <= 1
#pragma unroll
    for (int msk = 1; msk < 64; msk <<= 1) e += __shfl_xor(e, msk, 64);
    if (act) {
        float r = val - m - logf(e);
        long oidx = (long)n * 40 + lane;
        if (f32) ((float*)out)[oidx] = r;
        else     ((unsigned short*)out)[oidx] = f2b(r);
    }
}

// ---------- host ----------
extern "C" void kernel_launch(void* const* d_in, const int* in_sizes, int n_in,
                              void* d_out, int out_size, void* d_ws, size_t ws_size,
                              hipStream_t stream)
{
    const int* n_id = (const int*)d_in[0];
    const int* lidx = (const int*)d_in[1];
    const int* ei0  = (const int*)d_in[3];
    const int* et0  = (const int*)d_in[4];
    const int* ei1  = (const int*)d_in[5];
    const int* et1  = (const int*)d_in[6];
    const void* emb = d_in[7];
    const void* Wj0 = d_in[8];
    const void* Wi0 = d_in[9];
    const void* aj0 = d_in[10];
    const void* ai0 = d_in[11];
    const void* Wq0 = d_in[12];
    const void* Wk0 = d_in[13];
    const void* Wv0 = d_in[14];
    const void* sw0 = d_in[15];
    const void* sb0 = d_in[16];
    const void* Wr0 = d_in[17];
    const void* Wj1 = d_in[18];
    const void* Wi1 = d_in[19];
    const void* aj1 = d_in[20];
    const void* ai1 = d_in[21];
    const void* Wq1 = d_in[22];
    const void* Wk1 = d_in[23];
    const void* Wv1 = d_in[24];
    const void* sw1 = d_in[25];
    const void* sb1 = d_in[26];
    const void* Wr1 = d_in[27];
    const int E0 = in_sizes[4], E1 = in_sizes[6];

    // ---- workspace layout, peak ~78 MB ----
    // [A] x30k 7.68M | [B] hj0 15.36M | [C] hi0 15.36M | [D] x1 15.36M |
    // [E] per-chunk: den_c + z_c (contiguous, one memset) + qc/kc/vc | flag (last)
    // Layer-1 block (20.7M) overlays [A..C] (dead after layer-0 chunk loop).
    char* w = (char*)d_ws;
    size_t o = 0;
    auto take = [&](size_t b) { char* p = w + o; o += (b + 255) & ~(size_t)255; return p; };
    unsigned short* x30k = (unsigned short*)take((size_t)N1 * IN * 2);
    unsigned short* hj0  = (unsigned short*)take((size_t)N1 * HC0 * 2);
    unsigned short* hi0  = (unsigned short*)take((size_t)N1 * HC0 * 2);
    unsigned short* x1   = (unsigned short*)take((size_t)N1 * HC0 * 2);
    float* den_c = (float*)take((size_t)R * CH * 4 * 4);   // den_c + z_c contiguous
    float* z_c   = (float*)take((size_t)R * CH * HC0 * 4);
    unsigned short* qc = (unsigned short*)take((size_t)R * CH * HC0 * 2);
    unsigned short* kc = (unsigned short*)take((size_t)R * CH * HC0 * 2);
    unsigned short* vc = (unsigned short*)take((size_t)R * CH * HC0 * 2);
    int* dflag = (int*)take(256);
    // layer-1 block overlays [A..C] (max 20.7MB < 38.4MB, clear of x1 and dflag)
    size_t o1 = 0;
    auto take1 = [&](size_t b) { char* p = w + o1; o1 += (b + 255) & ~(size_t)255; return p; };
    unsigned short* hj1 = (unsigned short*)take1((size_t)N2 * C1 * 2);
    unsigned short* hi1 = (unsigned short*)take1((size_t)N2 * C1 * 2);
    float* self1 = (float*)take1((size_t)N2 * C1 * 4);
    float* den1  = (float*)take1((size_t)R * N2 * 4);
    float* z1    = (float*)take1((size_t)R * N2 * C1 * 4);
    unsigned short* q1b = (unsigned short*)take1((size_t)R * N2 * C1 * 2);
    unsigned short* k1b = (unsigned short*)take1((size_t)R * N2 * C1 * 2);
    unsigned short* v1b = (unsigned short*)take1((size_t)R * N2 * C1 * 2);

    // ---- dtype flavor detection (must precede all input-touching kernels) ----
    detect_k<<<1, 64, 0, stream>>>(emb, dflag);

    // ---- layer 0: features ----
    gather_k<<<(int)(((long)N1 * IN + 255) / 256), 256, 0, stream>>>(n_id, lidx, emb, x30k, N1, dflag);

    dim3 g0((HC0 + 63) / 64, (N1 + 63) / 64, 1);
    gemm_k<unsigned short, unsigned short><<<g0, 256, 0, stream>>>(x30k, Wj0, hj0, nullptr, dflag, N1, HC0, IN, 0, 0, 0);
    gemm_k<unsigned short, unsigned short><<<g0, 256, 0, stream>>>(x30k, Wi0, hi0, nullptr, dflag, N1, HC0, IN, 0, 0, 0);
    gemm_k<unsigned short, unsigned short><<<g0, 256, 0, stream>>>(x30k, sw0, x1, sb0, dflag, N1, HC0, IN, 0, 0, 0);

    // ---- layer 0: chunked edge-softmax + q/k/v + relation attention ----
    const size_t denz_bytes = (((size_t)R * CH * 4 * 4 + 255) & ~(size_t)255) + (size_t)R * CH * HC0 * 4;
    const long sB0 = (long)HC0 * HC0, sCc = (long)CH * HC0;
    for (int c = 0; c < N1 / CH; ++c) {
        const int n0 = c * CH;
        hipMemsetAsync(den_c, 0, denz_bytes, stream);
        edge_scatter_k<4, 64, CH><<<(E0 + 3) / 4, 256, 0, stream>>>(
            ei0, et0, E0, n0, hj0, hi0, aj0, ai0, z_c, den_c, dflag);
        long nv4 = (long)R * CH * HC0 / 4;
        norm_z_k<4, 64><<<(unsigned)((nv4 + 255) / 256), 256, 0, stream>>>(z_c, den_c, nv4);
        dim3 gq((HC0 + 63) / 64, (CH + 63) / 64, R);
        gemm_k<float, unsigned short><<<gq, 256, 0, stream>>>(z_c, Wq0, qc, nullptr, dflag, CH, HC0, HC0, sCc, sB0, sCc);
        gemm_k<float, unsigned short><<<gq, 256, 0, stream>>>(z_c, Wk0, kc, nullptr, dflag, CH, HC0, HC0, sCc, sB0, sCc);
        gemm_k<float, unsigned short><<<gq, 256, 0, stream>>>(z_c, Wv0, vc, nullptr, dflag, CH, HC0, HC0, sCc, sB0, sCc);
        fused_attn0_k<<<(CH + 3) / 4, 256, 0, stream>>>(qc, kc, vc, Wr0, x1, n0, CH, dflag);
    }

    // ---- layer 1 ----
    hipMemsetAsync(den1, 0, (size_t)R * N2 * 4, stream);
    hipMemsetAsync(z1, 0, (size_t)R * N2 * C1 * 4, stream);

    dim3 g1((C1 + 63) / 64, (N2 + 63) / 64, 1);
    gemm_k<unsigned short, unsigned short><<<g1, 256, 0, stream>>>(x1, Wj1, hj1, nullptr, dflag, N2, C1, HC0, 0, 0, 0);
    gemm_k<unsigned short, unsigned short><<<g1, 256, 0, stream>>>(x1, Wi1, hi1, nullptr, dflag, N2, C1, HC0, 0, 0, 0);
    gemm_k<unsigned short, float><<<g1, 256, 0, stream>>>(x1, sw1, self1, sb1, dflag, N2, C1, HC0, 0, 0, 0);

    edge_scatter_k<1, 40, N2><<<(E1 + 3) / 4, 256, 0, stream>>>(
        ei1, et1, E1, 0, hj1, hi1, aj1, ai1, z1, den1, dflag);

    long nv41 = (long)R * N2 * C1 / 4;
    norm_z_k<1, 40><<<(unsigned)((nv41 + 255) / 256), 256, 0, stream>>>(z1, den1, nv41);

    dim3 gq1((C1 + 63) / 64, (N2 + 63) / 64, R);
    long sA1 = (long)N2 * C1, sB1 = (long)C1 * C1;
    gemm_k<float, unsigned short><<<gq1, 256, 0, stream>>>(z1, Wq1, q1b, nullptr, dflag, N2, C1, C1, sA1, sB1, sA1);
    gemm_k<float, unsigned short><<<gq1, 256, 0, stream>>>(z1, Wk1, k1b, nullptr, dflag, N2, C1, C1, sA1, sB1, sA1);
    gemm_k<float, unsigned short><<<gq1, 256, 0, stream>>>(z1, Wv1, v1b, nullptr, dflag, N2, C1, C1, sA1, sB1, sA1);

    fused_attn1_k<<<(N2 + 3) / 4, 256, 0, stream>>>(q1b, k1b, v1b, Wr1, self1, d_out, N2, dflag);
}

// Round 5
// 1098.372 us; speedup vs baseline: 4.0505x; 4.0505x over previous
//
#include <hip/hip_runtime.h>
#include <hip/hip_bf16.h>

#define DI __device__ __forceinline__

// ---------- bf16 helpers (raw ushort bits) ----------
DI float b2f(unsigned short u) {
    union { unsigned int i; float f; } x; x.i = ((unsigned int)u) << 16; return x.f;
}
DI unsigned short f2b(float f) {
    union { float f; unsigned int i; } x; x.f = f;
    unsigned int r = x.i + 0x7fff + ((x.i >> 16) & 1);  // RNE
    return (unsigned short)(r >> 16);
}
// flavor-aware input load: f32!=0 -> fp32 array, else bf16 array
DI float ldin(const void* p, long i, int f32) {
    return f32 ? ((const float*)p)[i] : b2f(((const unsigned short*)p)[i]);
}
DI void stval(float* p, float v) { *p = v; }
DI void stval(unsigned short* p, float v) { *p = f2b(v); }

// ---------- constants ----------
static constexpr int N1 = 30000, N2 = 15000, R = 5;
static constexpr int IN = 128, HC0 = 256, C1 = 40;
static constexpr int CHQ = 7500;           // layer-0 qkv/attn chunk (4 chunks)
static constexpr float NEGBIG = -1e30f;    // finite "-inf" (NaN-proof masking)
static constexpr int LDK = 72;             // LDS K-stride (64 + 8 pad)

typedef short bf16x8 __attribute__((ext_vector_type(8)));
typedef float f32x4 __attribute__((ext_vector_type(4)));

// ---------- dtype flavor detection (fp32 read as bf16 -> huge/NaN exponents) ----------
__global__ void detect_k(const void* emb, int* flag)
{
    int lane = threadIdx.x;   // 64 threads
    int bad = 0;
    for (int j = 0; j < 4; ++j) {
        float f = b2f(((const unsigned short*)emb)[lane * 4 + j]);
        if (!(fabsf(f) < 1e8f)) bad = 1;   // catches NaN too
    }
    unsigned long long anybad = __ballot(bad != 0);
    if (lane == 0) *flag = (anybad != 0ull) ? 1 : 0;
}

// ---------- weight transpose: dst[b][n][k] = bf16(src[b][k][n]), 3 tensors ----------
__global__ __launch_bounds__(256) void transpose3_k(
    const void* s0, const void* s1, const void* s2,
    unsigned short* d0, unsigned short* d1, unsigned short* d2,
    const int* __restrict__ dflag, int K, int N, long per)
{
    const int f32 = *dflag;
    long t = (long)blockIdx.x * 256 + threadIdx.x;
    if (t >= per) return;
    const void* s = blockIdx.y == 0 ? s0 : blockIdx.y == 1 ? s1 : s2;
    unsigned short* d = blockIdx.y == 0 ? d0 : blockIdx.y == 1 ? d1 : d2;
    long kn = (long)K * N;
    long b = t / kn, rem = t % kn;
    long k = rem / N, n = rem % N;          // t fastest over n -> coalesced read
    d[(b * N + n) * K + k] = f2b(ldin(s, t, f32));
}

// ---------- gather x[:N1] = bf16(emb[lidx[n_id[n]]]) ----------
__global__ __launch_bounds__(256) void gather_k(
    const int* __restrict__ n_id, const int* __restrict__ lidx,
    const void* __restrict__ emb, unsigned short* __restrict__ x, int rows,
    const int* __restrict__ dflag)
{
    const int f32 = *dflag;
    long t = (long)blockIdx.x * 256 + threadIdx.x;
    long n = t >> 7, d = t & 127;
    if (n >= rows) return;
    long row = lidx[n_id[n]];
    x[n * IN + d] = f2b(ldin(emb, row * IN + d, f32));
}

// ---------- MFMA GEMM: C[b] = A[b] @ Bt[b]^T (+bias). A[M][K], Bt[N][K] bf16 ----------
// 128x128 block tile, 4 waves (2x2 of 64x64), BK=64, 16x16x32 bf16 MFMA.
// Layouts (guide-verified): A-frag m=lane&15,k=quad*8+j; B-frag n=lane&15,k=quad*8+j;
// C/D row=quad*4+reg, col=lane&15.
DI void stage_tile(const unsigned short* __restrict__ G, int rows, int K,
                   int r0, int k0, unsigned short* S, int tid)
{
    const int sr = tid >> 1, sq = (tid & 1) * 32;
    unsigned short* dst = S + sr * LDK + sq;
    const unsigned short* g = G + (long)(r0 + sr) * K + k0 + sq;
    const bool rowok = (r0 + sr) < rows;
    if (rowok && (k0 + sq + 32) <= K) {
        const uint4* gv = (const uint4*)g;
        uint4 a = gv[0], b = gv[1], c = gv[2], d = gv[3];
        *(uint4*)(dst) = a; *(uint4*)(dst + 8) = b;
        *(uint4*)(dst + 16) = c; *(uint4*)(dst + 24) = d;
    } else {
#pragma unroll 8
        for (int j = 0; j < 32; ++j) {
            int k = k0 + sq + j;
            dst[j] = (rowok && k < K) ? g[j] : (unsigned short)0;
        }
    }
}

template <typename OT>
__global__ __launch_bounds__(256) void gemm_mfma_k(
    const unsigned short* __restrict__ A, const unsigned short* __restrict__ Bt,
    OT* __restrict__ C, const void* __restrict__ bias,
    const int* __restrict__ dflag,
    int M, int N, int K, long sA, long sB, long sC)
{
    __shared__ unsigned short As[128 * LDK];
    __shared__ unsigned short Bs[128 * LDK];
    const int f32 = *dflag;
    const int bz = blockIdx.z;
    A += (long)bz * sA; Bt += (long)bz * sB; C += (long)bz * sC;
    const int tid = threadIdx.x;
    const int m0 = blockIdx.y * 128, n0 = blockIdx.x * 128;
    const int lane = tid & 63, wave = tid >> 6;
    const int wm = (wave & 1) * 64, wn = (wave >> 1) * 64;
    const int row16 = lane & 15, quad = lane >> 4;
    f32x4 acc[4][4];
#pragma unroll
    for (int i = 0; i < 4; ++i)
#pragma unroll
        for (int j = 0; j < 4; ++j) acc[i][j] = {0.f, 0.f, 0.f, 0.f};

    for (int k0 = 0; k0 < K; k0 += 64) {
        stage_tile(A, M, K, m0, k0, As, tid);
        stage_tile(Bt, N, K, n0, k0, Bs, tid);
        __syncthreads();
#pragma unroll
        for (int ks = 0; ks < 64; ks += 32) {
            bf16x8 af[4], bfr[4];
#pragma unroll
            for (int i = 0; i < 4; ++i)
                af[i] = *(const bf16x8*)(As + (wm + i * 16 + row16) * LDK + ks + quad * 8);
#pragma unroll
            for (int j = 0; j < 4; ++j)
                bfr[j] = *(const bf16x8*)(Bs + (wn + j * 16 + row16) * LDK + ks + quad * 8);
#pragma unroll
            for (int i = 0; i < 4; ++i)
#pragma unroll
                for (int j = 0; j < 4; ++j)
                    acc[i][j] = __builtin_amdgcn_mfma_f32_16x16x32_bf16(
                        af[i], bfr[j], acc[i][j], 0, 0, 0);
        }
        __syncthreads();
    }
#pragma unroll
    for (int i = 0; i < 4; ++i) {
#pragma unroll
        for (int reg = 0; reg < 4; ++reg) {
            const int gr = m0 + wm + i * 16 + quad * 4 + reg;
            if (gr >= M) continue;
#pragma unroll
            for (int j = 0; j < 4; ++j) {
                const int gc = n0 + wn + j * 16 + row16;
                if (gc >= N) continue;
                float v = acc[i][j][reg];
                if (bias) v += ldin(bias, gc, f32);
                stval(&C[(long)gr * N + gc], v);
            }
        }
    }
}

// ---------- per-(node,r,h) attention dots: an[n,r,h] = sum_c att[r,h,c]*hx[n,h,c] ----------
__global__ __launch_bounds__(256) void alpha_node0_k(
    const unsigned short* __restrict__ hj, const unsigned short* __restrict__ hi,
    const void* __restrict__ attj, const void* __restrict__ atti,
    const int* __restrict__ dflag,
    float* __restrict__ ajn, float* __restrict__ ain, int Nn)
{
    const int f32 = *dflag;
    int n = (int)((blockIdx.x * 256u + threadIdx.x) >> 6);
    int lane = threadIdx.x & 63;
    if (n >= Nn) return;
    int dd = lane * 4;                 // h = lane>>4
    ushort4 xj = *(const ushort4*)(hj + (long)n * 256 + dd);
    ushort4 xi = *(const ushort4*)(hi + (long)n * 256 + dd);
    float xjf[4] = {b2f(xj.x), b2f(xj.y), b2f(xj.z), b2f(xj.w)};
    float xif[4] = {b2f(xi.x), b2f(xi.y), b2f(xi.z), b2f(xi.w)};
#pragma unroll
    for (int r = 0; r < 5; ++r) {
        long ab = (long)r * 256 + dd;
        float pj = 0.f, pi = 0.f;
#pragma unroll
        for (int j = 0; j < 4; ++j) {
            pj += ldin(attj, ab + j, f32) * xjf[j];
            pi += ldin(atti, ab + j, f32) * xif[j];
        }
#pragma unroll
        for (int m = 1; m < 16; m <<= 1) {
            pj += __shfl_xor(pj, m, 64);
            pi += __shfl_xor(pi, m, 64);
        }
        if ((lane & 15) == 0) {
            ajn[((long)n * 5 + r) * 4 + (lane >> 4)] = pj;
            ain[((long)n * 5 + r) * 4 + (lane >> 4)] = pi;
        }
    }
}

__global__ __launch_bounds__(256) void alpha_node1_k(
    const unsigned short* __restrict__ hj, const unsigned short* __restrict__ hi,
    const void* __restrict__ attj, const void* __restrict__ atti,
    const int* __restrict__ dflag,
    float* __restrict__ ajn, float* __restrict__ ain, int Nn)
{
    const int f32 = *dflag;
    int n = (int)((blockIdx.x * 256u + threadIdx.x) >> 6);
    int lane = threadIdx.x & 63;
    if (n >= Nn) return;
    bool act = lane < 40;
    float xj = act ? b2f(hj[(long)n * 40 + lane]) : 0.f;
    float xi = act ? b2f(hi[(long)n * 40 + lane]) : 0.f;
#pragma unroll
    for (int r = 0; r < 5; ++r) {
        float pj = act ? ldin(attj, (long)r * 40 + lane, f32) * xj : 0.f;
        float pi = act ? ldin(atti, (long)r * 40 + lane, f32) * xi : 0.f;
#pragma unroll
        for (int m = 1; m < 64; m <<= 1) {
            pj += __shfl_xor(pj, m, 64);
            pi += __shfl_xor(pi, m, 64);
        }
        if (lane == 0) {
            ajn[(long)n * 5 + r] = pj;
            ain[(long)n * 5 + r] = pi;
        }
    }
}

// ---------- CSR build ----------
__global__ __launch_bounds__(256) void hist_k(const int* __restrict__ ei, int E, int* __restrict__ cnt)
{
    int e = blockIdx.x * 256 + threadIdx.x;
    if (e < E) atomicAdd(&cnt[ei[E + e]], 1);
}
__global__ void scan_k(const int* __restrict__ cnt, int* __restrict__ off,
                       int* __restrict__ cursor, int n)
{
    __shared__ int buf[256];
    __shared__ int carry;
    if (threadIdx.x == 0) carry = 0;
    __syncthreads();
    for (int base = 0; base < n; base += 256) {
        int i = base + threadIdx.x;
        int v = (i < n) ? cnt[i] : 0;
        buf[threadIdx.x] = v;
        __syncthreads();
        for (int s = 1; s < 256; s <<= 1) {
            int t = (threadIdx.x >= s) ? buf[threadIdx.x - s] : 0;
            __syncthreads();
            buf[threadIdx.x] += t;
            __syncthreads();
        }
        int excl = carry + buf[threadIdx.x] - v;
        if (i < n) { off[i] = excl; cursor[i] = excl; }
        __syncthreads();
        if (threadIdx.x == 255) carry += buf[255];
        __syncthreads();
    }
    if (threadIdx.x == 0) off[n] = carry;
}
__global__ __launch_bounds__(256) void scatter_k(const int* __restrict__ ei, int E,
                                                 int* __restrict__ cursor, int* __restrict__ elist)
{
    int e = blockIdx.x * 256 + threadIdx.x;
    if (e < E) {
        int p = atomicAdd(&cursor[ei[E + e]], 1);
        elist[p] = e;
    }
}

// ---------- CSR aggregation, layer 0: one wave per tgt; z bf16, no atomics ----------
__global__ __launch_bounds__(256) void aggregate0_k(
    const int* __restrict__ ei, const int* __restrict__ et,
    const int* __restrict__ off, const int* __restrict__ elist,
    const unsigned short* __restrict__ hj,
    const float* __restrict__ ajn, const float* __restrict__ ain,
    unsigned short* __restrict__ z, int Nn, int E)
{
    int tgt = (int)((blockIdx.x * 256u + threadIdx.x) >> 6);
    int lane = threadIdx.x & 63;
    if (tgt >= Nn) return;
    int dd = lane * 4, h = lane >> 4;
    float ainv[5];
#pragma unroll
    for (int r = 0; r < 5; ++r) ainv[r] = ain[((long)tgt * 5 + r) * 4 + h];
    float acc[5][4] = {};
    float den[5] = {};
    int s = off[tgt], epd = off[tgt + 1];
    for (int i = s; i < epd; ++i) {
        int e = elist[i];
        int src = ei[e], r_e = et[e];
        float aj = ajn[((long)src * 5 + r_e) * 4 + h];
        float aiv = ainv[0];
#pragma unroll
        for (int r = 1; r < 5; ++r) aiv = (r_e == r) ? ainv[r] : aiv;
        float al = aj + aiv;
        al = al > 0.f ? al : 0.2f * al;
        al = fminf(al, 60.f);
        float wgt = expf(al);
        ushort4 xj = *(const ushort4*)(hj + (long)src * 256 + dd);
        float x0 = b2f(xj.x), x1 = b2f(xj.y), x2 = b2f(xj.z), x3 = b2f(xj.w);
#pragma unroll
        for (int r = 0; r < 5; ++r) {
            float ws = (r == r_e) ? wgt : 0.f;
            den[r] += ws;
            acc[r][0] += ws * x0; acc[r][1] += ws * x1;
            acc[r][2] += ws * x2; acc[r][3] += ws * x3;
        }
    }
#pragma unroll
    for (int r = 0; r < 5; ++r) {
        float inv = 1.f / fmaxf(den[r], 1e-16f);
        ushort4 o;
        o.x = f2b(acc[r][0] * inv); o.y = f2b(acc[r][1] * inv);
        o.z = f2b(acc[r][2] * inv); o.w = f2b(acc[r][3] * inv);
        *(ushort4*)(z + ((long)r * Nn + tgt) * 256 + dd) = o;
    }
}

// ---------- CSR aggregation, layer 1 (H=1,C=40) ----------
__global__ __launch_bounds__(256) void aggregate1_k(
    const int* __restrict__ ei, const int* __restrict__ et,
    const int* __restrict__ off, const int* __restrict__ elist,
    const unsigned short* __restrict__ hj,
    const float* __restrict__ ajn, const float* __restrict__ ain,
    unsigned short* __restrict__ z, int Nn, int E)
{
    int tgt = (int)((blockIdx.x * 256u + threadIdx.x) >> 6);
    int lane = threadIdx.x & 63;
    if (tgt >= Nn) return;
    bool act = lane < 40;
    float ainv[5];
#pragma unroll
    for (int r = 0; r < 5; ++r) ainv[r] = ain[(long)tgt * 5 + r];
    float acc[5] = {};
    float den[5] = {};
    int s = off[tgt], epd = off[tgt + 1];
    for (int i = s; i < epd; ++i) {
        int e = elist[i];
        int src = ei[e], r_e = et[e];
        float aj = ajn[(long)src * 5 + r_e];
        float aiv = ainv[0];
#pragma unroll
        for (int r = 1; r < 5; ++r) aiv = (r_e == r) ? ainv[r] : aiv;
        float al = aj + aiv;
        al = al > 0.f ? al : 0.2f * al;
        al = fminf(al, 60.f);
        float wgt = expf(al);
        float xj = act ? b2f(hj[(long)src * 40 + lane]) : 0.f;
#pragma unroll
        for (int r = 0; r < 5; ++r) {
            float ws = (r == r_e) ? wgt : 0.f;
            den[r] += ws;
            acc[r] += ws * xj;
        }
    }
    if (act) {
#pragma unroll
        for (int r = 0; r < 5; ++r) {
            float inv = 1.f / fmaxf(den[r], 1e-16f);
            z[((long)r * Nn + tgt) * 40 + lane] = f2b(acc[r] * inv);
        }
    }
}

// ---------- fused relation attention, layer 0 (H=4,C=64): one wave per node ----------
__global__ __launch_bounds__(256) void fused_attn0_k(
    const unsigned short* __restrict__ qb, const unsigned short* __restrict__ kb,
    const unsigned short* __restrict__ vb, const void* __restrict__ wrel,
    unsigned short* __restrict__ x1, int n0, int nloc,
    const int* __restrict__ dflag)
{
    const int f32 = *dflag;
    int nl = (int)((blockIdx.x * 256u + threadIdx.x) >> 6);
    int lane = threadIdx.x & 63;
    if (nl >= nloc) return;
    int n = n0 + nl;
    int dd = lane * 4;
    float qf[5][4], kf[5][4];
#pragma unroll
    for (int r = 0; r < 5; ++r) {
        ushort4 qv = *(const ushort4*)(qb + ((long)r * CHQ + nl) * 256 + dd);
        ushort4 kv = *(const ushort4*)(kb + ((long)r * CHQ + nl) * 256 + dd);
        qf[r][0] = b2f(qv.x); qf[r][1] = b2f(qv.y); qf[r][2] = b2f(qv.z); qf[r][3] = b2f(qv.w);
        kf[r][0] = b2f(kv.x); kf[r][1] = b2f(kv.y); kf[r][2] = b2f(kv.z); kf[r][3] = b2f(kv.w);
    }
    float psi[5][5];
#pragma unroll
    for (int r = 0; r < 5; ++r)
#pragma unroll
        for (int s = 0; s < 5; ++s) {
            float p = qf[r][0] * kf[s][0] + qf[r][1] * kf[s][1] +
                      qf[r][2] * kf[s][2] + qf[r][3] * kf[s][3];
            p += __shfl_xor(p, 1, 64); p += __shfl_xor(p, 2, 64);
            p += __shfl_xor(p, 4, 64); p += __shfl_xor(p, 8, 64);
            psi[r][s] = p;
        }
    float pw[5] = {0.f, 0.f, 0.f, 0.f, 0.f};
#pragma unroll
    for (int r = 0; r < 5; ++r) {
        float rowsum = psi[r][0] + psi[r][1] + psi[r][2] + psi[r][3] + psi[r][4];
        float vals[5], m = NEGBIG;
#pragma unroll
        for (int s = 0; s < 5; ++s) {
            float v = (psi[r][s] == 0.f && rowsum != 0.f) ? NEGBIG : psi[r][s];
            vals[s] = v; m = fmaxf(m, v);
        }
        float es[5], sum = 0.f;
#pragma unroll
        for (int s = 0; s < 5; ++s) { es[s] = expf(vals[s] - m); sum += es[s]; }
        float wr = ldin(wrel, r, f32) / sum;
#pragma unroll
        for (int s = 0; s < 5; ++s) pw[s] += wr * es[s];
    }
    float acc[4] = {0.f, 0.f, 0.f, 0.f};
#pragma unroll
    for (int s = 0; s < 5; ++s) {
        ushort4 vv = *(const ushort4*)(vb + ((long)s * CHQ + nl) * 256 + dd);
        acc[0] += pw[s] * b2f(vv.x); acc[1] += pw[s] * b2f(vv.y);
        acc[2] += pw[s] * b2f(vv.z); acc[3] += pw[s] * b2f(vv.w);
    }
    ushort4* xp = (ushort4*)(x1 + (long)n * 256 + dd);
    ushort4 sv = *xp;
    sv.x = f2b(fmaxf(b2f(sv.x) + acc[0], 0.f));
    sv.y = f2b(fmaxf(b2f(sv.y) + acc[1], 0.f));
    sv.z = f2b(fmaxf(b2f(sv.z) + acc[2], 0.f));
    sv.w = f2b(fmaxf(b2f(sv.w) + acc[3], 0.f));
    *xp = sv;
}

// ---------- fused relation attention, layer 1 (H=1,C=40) + log_softmax -> d_out ----------
__global__ __launch_bounds__(256) void fused_attn1_k(
    const unsigned short* __restrict__ qb, const unsigned short* __restrict__ kb,
    const unsigned short* __restrict__ vb, const void* __restrict__ wrel,
    const float* __restrict__ self1, void* __restrict__ out, int N,
    const int* __restrict__ dflag)
{
    const int f32 = *dflag;
    int n = (int)((blockIdx.x * 256u + threadIdx.x) >> 6);
    int lane = threadIdx.x & 63;
    if (n >= N) return;
    bool act = lane < 40;
    float qf[5], kf[5];
#pragma unroll
    for (int r = 0; r < 5; ++r) {
        long o = ((long)r * N + n) * 40 + lane;
        qf[r] = act ? b2f(qb[o]) : 0.f;
        kf[r] = act ? b2f(kb[o]) : 0.f;
    }
    float psi[5][5];
#pragma unroll
    for (int r = 0; r < 5; ++r)
#pragma unroll
        for (int s = 0; s < 5; ++s) {
            float p = qf[r] * kf[s];
            p += __shfl_xor(p, 1, 64);  p += __shfl_xor(p, 2, 64);
            p += __shfl_xor(p, 4, 64);  p += __shfl_xor(p, 8, 64);
            p += __shfl_xor(p, 16, 64); p += __shfl_xor(p, 32, 64);
            psi[r][s] = p;
        }
    float pw[5] = {0.f, 0.f, 0.f, 0.f, 0.f};
#pragma unroll
    for (int r = 0; r < 5; ++r) {
        float rowsum = psi[r][0] + psi[r][1] + psi[r][2] + psi[r][3] + psi[r][4];
        float vals[5], m = NEGBIG;
#pragma unroll
        for (int s = 0; s < 5; ++s) {
            float v = (psi[r][s] == 0.f && rowsum != 0.f) ? NEGBIG : psi[r][s];
            vals[s] = v; m = fmaxf(m, v);
        }
        float es[5], sum = 0.f;
#pragma unroll
        for (int s = 0; s < 5; ++s) { es[s] = expf(vals[s] - m); sum += es[s]; }
        float wr = ldin(wrel, r, f32) / sum;
#pragma unroll
        for (int s = 0; s < 5; ++s) pw[s] += wr * es[s];
    }
    float val = NEGBIG;
    if (act) {
        float acc = 0.f;
#pragma unroll
        for (int s = 0; s < 5; ++s) acc += pw[s] * b2f(vb[((long)s * N + n) * 40 + lane]);
        val = self1[(long)n * 40 + lane] + acc;
    }
    float m = val;
#pragma unroll
    for (int msk = 1; msk < 64; msk <<= 1) m = fmaxf(m, __shfl_xor(m, msk, 64));
    float e = act ? expf(val - m) : 0.f;
#pragma unroll
    for (int msk = 1; msk < 64; msk <<= 1) e += __shfl_xor(e, msk, 64);
    if (act) {
        float r = val - m - logf(e);
        long oidx = (long)n * 40 + lane;
        if (f32) ((float*)out)[oidx] = r;
        else     ((unsigned short*)out)[oidx] = f2b(r);
    }
}

// ---------- host ----------
extern "C" void kernel_launch(void* const* d_in, const int* in_sizes, int n_in,
                              void* d_out, int out_size, void* d_ws, size_t ws_size,
                              hipStream_t stream)
{
    const int* n_id = (const int*)d_in[0];
    const int* lidx = (const int*)d_in[1];
    const int* ei0  = (const int*)d_in[3];
    const int* et0  = (const int*)d_in[4];
    const int* ei1  = (const int*)d_in[5];
    const int* et1  = (const int*)d_in[6];
    const void* emb = d_in[7];
    const void* Wj0 = d_in[8];  const void* Wi0 = d_in[9];
    const void* aj0 = d_in[10]; const void* ai0 = d_in[11];
    const void* Wq0 = d_in[12]; const void* Wk0 = d_in[13]; const void* Wv0 = d_in[14];
    const void* sw0 = d_in[15]; const void* sb0 = d_in[16]; const void* Wr0 = d_in[17];
    const void* Wj1 = d_in[18]; const void* Wi1 = d_in[19];
    const void* aj1 = d_in[20]; const void* ai1 = d_in[21];
    const void* Wq1 = d_in[22]; const void* Wk1 = d_in[23]; const void* Wv1 = d_in[24];
    const void* sw1 = d_in[25]; const void* sb1 = d_in[26]; const void* Wr1 = d_in[27];
    const int E0 = in_sizes[4], E1 = in_sizes[6];

    // ---- workspace layout, peak ~195 MB (< 210 MB known-good from R2) ----
    char* w = (char*)d_ws;
    size_t o = 0;
    auto take = [&](size_t b) { char* p = w + o; o += (b + 255) & ~(size_t)255; return p; };
    unsigned short* x30k = (unsigned short*)take((size_t)N1 * IN * 2);
    unsigned short* hj0  = (unsigned short*)take((size_t)N1 * HC0 * 2);
    unsigned short* hi0  = (unsigned short*)take((size_t)N1 * HC0 * 2);
    unsigned short* x1   = (unsigned short*)take((size_t)N1 * HC0 * 2);
    float* ajn0 = (float*)take((size_t)N1 * R * 4 * 4);
    float* ain0 = (float*)take((size_t)N1 * R * 4 * 4);
    int* cnt    = (int*)take((size_t)(N1 + 1) * 4);
    int* off    = (int*)take((size_t)(N1 + 1) * 4);
    int* cursor = (int*)take((size_t)(N1 + 1) * 4);
    int* elist  = (int*)take((size_t)E0 * 4);
    unsigned short* z0 = (unsigned short*)take((size_t)R * N1 * HC0 * 2);
    unsigned short* qc = (unsigned short*)take((size_t)R * CHQ * HC0 * 2);
    unsigned short* kc = (unsigned short*)take((size_t)R * CHQ * HC0 * 2);
    unsigned short* vc = (unsigned short*)take((size_t)R * CHQ * HC0 * 2);
    // transposed weights (bf16)
    unsigned short* wjt0 = (unsigned short*)take((size_t)HC0 * IN * 2);
    unsigned short* wit0 = (unsigned short*)take((size_t)HC0 * IN * 2);
    unsigned short* swt0 = (unsigned short*)take((size_t)HC0 * IN * 2);
    unsigned short* wqt0 = (unsigned short*)take((size_t)R * HC0 * HC0 * 2);
    unsigned short* wkt0 = (unsigned short*)take((size_t)R * HC0 * HC0 * 2);
    unsigned short* wvt0 = (unsigned short*)take((size_t)R * HC0 * HC0 * 2);
    unsigned short* wjt1 = (unsigned short*)take((size_t)C1 * HC0 * 2);
    unsigned short* wit1 = (unsigned short*)take((size_t)C1 * HC0 * 2);
    unsigned short* swt1 = (unsigned short*)take((size_t)C1 * HC0 * 2);
    unsigned short* wqt1 = (unsigned short*)take((size_t)R * C1 * C1 * 2);
    unsigned short* wkt1 = (unsigned short*)take((size_t)R * C1 * C1 * 2);
    unsigned short* wvt1 = (unsigned short*)take((size_t)R * C1 * C1 * 2);
    int* dflag = (int*)take(256);
    // layer-1 block overlays [x30k|hj0|hi0] (38.4 MB; all dead before first write)
    size_t o1 = 0;
    auto take1 = [&](size_t b) { char* p = w + o1; o1 += (b + 255) & ~(size_t)255; return p; };
    unsigned short* hj1 = (unsigned short*)take1((size_t)N2 * C1 * 2);
    unsigned short* hi1 = (unsigned short*)take1((size_t)N2 * C1 * 2);
    float* self1 = (float*)take1((size_t)N2 * C1 * 4);
    float* ajn1  = (float*)take1((size_t)N2 * R * 4);
    float* ain1  = (float*)take1((size_t)N2 * R * 4);
    unsigned short* z1  = (unsigned short*)take1((size_t)R * N2 * C1 * 2);
    unsigned short* q1b = (unsigned short*)take1((size_t)R * N2 * C1 * 2);
    unsigned short* k1b = (unsigned short*)take1((size_t)R * N2 * C1 * 2);
    unsigned short* v1b = (unsigned short*)take1((size_t)R * N2 * C1 * 2);

    // ---- dtype flavor detection ----
    detect_k<<<1, 64, 0, stream>>>(emb, dflag);

    // ---- weight transposes (flavored read -> bf16 [N][K]) ----
    {
        long p1 = (long)IN * HC0;
        transpose3_k<<<dim3((unsigned)((p1 + 255) / 256), 3), 256, 0, stream>>>(
            Wj0, Wi0, sw0, wjt0, wit0, swt0, dflag, IN, HC0, p1);
        long p2 = (long)R * HC0 * HC0;
        transpose3_k<<<dim3((unsigned)((p2 + 255) / 256), 3), 256, 0, stream>>>(
            Wq0, Wk0, Wv0, wqt0, wkt0, wvt0, dflag, HC0, HC0, p2);
        long p3 = (long)HC0 * C1;
        transpose3_k<<<dim3((unsigned)((p3 + 255) / 256), 3), 256, 0, stream>>>(
            Wj1, Wi1, sw1, wjt1, wit1, swt1, dflag, HC0, C1, p3);
        long p4 = (long)R * C1 * C1;
        transpose3_k<<<dim3((unsigned)((p4 + 255) / 256), 3), 256, 0, stream>>>(
            Wq1, Wk1, Wv1, wqt1, wkt1, wvt1, dflag, C1, C1, p4);
    }

    // ---- layer 0: features (MFMA) ----
    gather_k<<<(int)(((long)N1 * IN + 255) / 256), 256, 0, stream>>>(n_id, lidx, emb, x30k, N1, dflag);
    {
        dim3 g(2, (N1 + 127) / 128, 1);
        gemm_mfma_k<unsigned short><<<g, 256, 0, stream>>>(x30k, wjt0, hj0, nullptr, dflag, N1, HC0, IN, 0, 0, 0);
        gemm_mfma_k<unsigned short><<<g, 256, 0, stream>>>(x30k, wit0, hi0, nullptr, dflag, N1, HC0, IN, 0, 0, 0);
        gemm_mfma_k<unsigned short><<<g, 256, 0, stream>>>(x30k, swt0, x1, sb0, dflag, N1, HC0, IN, 0, 0, 0);
    }

    // ---- layer 0: alpha precompute + CSR + aggregation ----
    alpha_node0_k<<<(N1 + 3) / 4, 256, 0, stream>>>(hj0, hi0, aj0, ai0, dflag, ajn0, ain0, N1);
    hipMemsetAsync(cnt, 0, (size_t)(N1 + 1) * 4, stream);
    hist_k<<<(E0 + 255) / 256, 256, 0, stream>>>(ei0, E0, cnt);
    scan_k<<<1, 256, 0, stream>>>(cnt, off, cursor, N1);
    scatter_k<<<(E0 + 255) / 256, 256, 0, stream>>>(ei0, E0, cursor, elist);
    aggregate0_k<<<(N1 + 3) / 4, 256, 0, stream>>>(ei0, et0, off, elist, hj0, ajn0, ain0, z0, N1, E0);

    // ---- layer 0: chunked q/k/v (MFMA) + relation attention ----
    for (int c = 0; c < N1 / CHQ; ++c) {
        const unsigned short* zc = z0 + (long)c * CHQ * HC0;
        dim3 gq(2, (CHQ + 127) / 128, R);
        long sA = (long)N1 * HC0, sB = (long)HC0 * HC0, sC = (long)CHQ * HC0;
        gemm_mfma_k<unsigned short><<<gq, 256, 0, stream>>>(zc, wqt0, qc, nullptr, dflag, CHQ, HC0, HC0, sA, sB, sC);
        gemm_mfma_k<unsigned short><<<gq, 256, 0, stream>>>(zc, wkt0, kc, nullptr, dflag, CHQ, HC0, HC0, sA, sB, sC);
        gemm_mfma_k<unsigned short><<<gq, 256, 0, stream>>>(zc, wvt0, vc, nullptr, dflag, CHQ, HC0, HC0, sA, sB, sC);
        fused_attn0_k<<<(CHQ + 3) / 4, 256, 0, stream>>>(qc, kc, vc, Wr0, x1, c * CHQ, CHQ, dflag);
    }

    // ---- layer 1 ----
    {
        dim3 g(1, (N2 + 127) / 128, 1);
        gemm_mfma_k<unsigned short><<<g, 256, 0, stream>>>(x1, wjt1, hj1, nullptr, dflag, N2, C1, HC0, 0, 0, 0);
        gemm_mfma_k<unsigned short><<<g, 256, 0, stream>>>(x1, wit1, hi1, nullptr, dflag, N2, C1, HC0, 0, 0, 0);
        gemm_mfma_k<float><<<g, 256, 0, stream>>>(x1, swt1, self1, sb1, dflag, N2, C1, HC0, 0, 0, 0);
    }
    alpha_node1_k<<<(N2 + 3) / 4, 256, 0, stream>>>(hj1, hi1, aj1, ai1, dflag, ajn1, ain1, N2);
    hipMemsetAsync(cnt, 0, (size_t)(N2 + 1) * 4, stream);
    hist_k<<<(E1 + 255) / 256, 256, 0, stream>>>(ei1, E1, cnt);
    scan_k<<<1, 256, 0, stream>>>(cnt, off, cursor, N2);
    scatter_k<<<(E1 + 255) / 256, 256, 0, stream>>>(ei1, E1, cursor, elist);
    aggregate1_k<<<(N2 + 3) / 4, 256, 0, stream>>>(ei1, et1, off, elist, hj1, ajn1, ain1, z1, N2, E1);
    {
        dim3 gq(1, (N2 + 127) / 128, R);
        long sA = (long)N2 * C1, sB = (long)C1 * C1, sC = (long)N2 * C1;
        gemm_mfma_k<unsigned short><<<gq, 256, 0, stream>>>(z1, wqt1, q1b, nullptr, dflag, N2, C1, C1, sA, sB, sC);
        gemm_mfma_k<unsigned short><<<gq, 256, 0, stream>>>(z1, wkt1, k1b, nullptr, dflag, N2, C1, C1, sA, sB, sC);
        gemm_mfma_k<unsigned short><<<gq, 256, 0, stream>>>(z1, wvt1, v1b, nullptr, dflag, N2, C1, C1, sA, sB, sC);
    }
    fused_attn1_k<<<(N2 + 3) / 4, 256, 0, stream>>>(q1b, k1b, v1b, Wr1, self1, d_out, N2, dflag);
}

// Round 6
// 827.731 us; speedup vs baseline: 5.3749x; 1.3270x over previous
//
#include <hip/hip_runtime.h>
#include <hip/hip_bf16.h>

#define DI __device__ __forceinline__

// ---------- bf16 helpers (raw ushort bits) ----------
DI float b2f(unsigned short u) {
    union { unsigned int i; float f; } x; x.i = ((unsigned int)u) << 16; return x.f;
}
DI unsigned short f2b(float f) {
    union { float f; unsigned int i; } x; x.f = f;
    unsigned int r = x.i + 0x7fff + ((x.i >> 16) & 1);  // RNE
    return (unsigned short)(r >> 16);
}
// flavor-aware input load: f32!=0 -> fp32 array, else bf16 array
DI float ldin(const void* p, long i, int f32) {
    return f32 ? ((const float*)p)[i] : b2f(((const unsigned short*)p)[i]);
}
DI void stval(float* p, float v) { *p = v; }
DI void stval(unsigned short* p, float v) { *p = f2b(v); }

// ---------- constants ----------
static constexpr int N1 = 30000, N2 = 15000, R = 5;
static constexpr int IN = 128, HC0 = 256, C1 = 40;
static constexpr int CHQ = 7500;           // layer-0 qkv/attn chunk (4 chunks)
static constexpr float NEGBIG = -1e30f;    // finite "-inf" (NaN-proof masking)
static constexpr int LDK = 72;             // LDS K-stride (64 + 8 pad)

typedef short bf16x8 __attribute__((ext_vector_type(8)));
typedef float f32x4 __attribute__((ext_vector_type(4)));

// ---------- dtype flavor detection (fp32 read as bf16 -> huge/NaN exponents) ----------
__global__ void detect_k(const void* emb, int* flag)
{
    int lane = threadIdx.x;   // 64 threads
    int bad = 0;
    for (int j = 0; j < 4; ++j) {
        float f = b2f(((const unsigned short*)emb)[lane * 4 + j]);
        if (!(fabsf(f) < 1e8f)) bad = 1;   // catches NaN too
    }
    unsigned long long anybad = __ballot(bad != 0);
    if (lane == 0) *flag = (anybad != 0ull) ? 1 : 0;
}

// ---------- weight transpose: dst[b][n][k] = bf16(src[b][k][n]), 3 tensors ----------
__global__ __launch_bounds__(256) void transpose3_k(
    const void* s0, const void* s1, const void* s2,
    unsigned short* d0, unsigned short* d1, unsigned short* d2,
    const int* __restrict__ dflag, int K, int N, long per)
{
    const int f32 = *dflag;
    long t = (long)blockIdx.x * 256 + threadIdx.x;
    if (t >= per) return;
    const void* s = blockIdx.y == 0 ? s0 : blockIdx.y == 1 ? s1 : s2;
    unsigned short* d = blockIdx.y == 0 ? d0 : blockIdx.y == 1 ? d1 : d2;
    long kn = (long)K * N;
    long b = t / kn, rem = t % kn;
    long k = rem / N, n = rem % N;          // t fastest over n -> coalesced read
    d[(b * N + n) * K + k] = f2b(ldin(s, t, f32));
}

// ---------- gather x[:N1] = bf16(emb[lidx[n_id[n]]]) ----------
__global__ __launch_bounds__(256) void gather_k(
    const int* __restrict__ n_id, const int* __restrict__ lidx,
    const void* __restrict__ emb, unsigned short* __restrict__ x, int rows,
    const int* __restrict__ dflag)
{
    const int f32 = *dflag;
    long t = (long)blockIdx.x * 256 + threadIdx.x;
    long n = t >> 7, d = t & 127;
    if (n >= rows) return;
    long row = lidx[n_id[n]];
    x[n * IN + d] = f2b(ldin(emb, row * IN + d, f32));
}

// ---------- MFMA GEMM core: 128x128 tile, 4 waves, BK=64, 16x16x32 bf16 ----------
DI void stage_tile(const unsigned short* __restrict__ G, int rows, int K,
                   int r0, int k0, unsigned short* S, int tid)
{
    const int sr = tid >> 1, sq = (tid & 1) * 32;
    unsigned short* dst = S + sr * LDK + sq;
    const unsigned short* g = G + (long)(r0 + sr) * K + k0 + sq;
    const bool rowok = (r0 + sr) < rows;
    if (rowok && (k0 + sq + 32) <= K) {
        const uint4* gv = (const uint4*)g;
        uint4 a = gv[0], b = gv[1], c = gv[2], d = gv[3];
        *(uint4*)(dst) = a; *(uint4*)(dst + 8) = b;
        *(uint4*)(dst + 16) = c; *(uint4*)(dst + 24) = d;
    } else {
#pragma unroll 8
        for (int j = 0; j < 32; ++j) {
            int k = k0 + sq + j;
            dst[j] = (rowok && k < K) ? g[j] : (unsigned short)0;
        }
    }
}

template <typename OT>
DI void gemm_mfma_body(
    const unsigned short* __restrict__ A, const unsigned short* __restrict__ Bt,
    OT* __restrict__ C, const void* __restrict__ bias, int f32,
    int M, int N, int K, unsigned short* As, unsigned short* Bs)
{
    const int tid = threadIdx.x;
    const int m0 = blockIdx.y * 128, n0 = blockIdx.x * 128;
    const int lane = tid & 63, wave = tid >> 6;
    const int wm = (wave & 1) * 64, wn = (wave >> 1) * 64;
    const int row16 = lane & 15, quad = lane >> 4;
    f32x4 acc[4][4];
#pragma unroll
    for (int i = 0; i < 4; ++i)
#pragma unroll
        for (int j = 0; j < 4; ++j) acc[i][j] = {0.f, 0.f, 0.f, 0.f};

    for (int k0 = 0; k0 < K; k0 += 64) {
        stage_tile(A, M, K, m0, k0, As, tid);
        stage_tile(Bt, N, K, n0, k0, Bs, tid);
        __syncthreads();
#pragma unroll
        for (int ks = 0; ks < 64; ks += 32) {
            bf16x8 af[4], bfr[4];
#pragma unroll
            for (int i = 0; i < 4; ++i)
                af[i] = *(const bf16x8*)(As + (wm + i * 16 + row16) * LDK + ks + quad * 8);
#pragma unroll
            for (int j = 0; j < 4; ++j)
                bfr[j] = *(const bf16x8*)(Bs + (wn + j * 16 + row16) * LDK + ks + quad * 8);
#pragma unroll
            for (int i = 0; i < 4; ++i)
#pragma unroll
                for (int j = 0; j < 4; ++j)
                    acc[i][j] = __builtin_amdgcn_mfma_f32_16x16x32_bf16(
                        af[i], bfr[j], acc[i][j], 0, 0, 0);
        }
        __syncthreads();
    }
#pragma unroll
    for (int i = 0; i < 4; ++i) {
#pragma unroll
        for (int reg = 0; reg < 4; ++reg) {
            const int gr = m0 + wm + i * 16 + quad * 4 + reg;
            if (gr >= M) continue;
#pragma unroll
            for (int j = 0; j < 4; ++j) {
                const int gc = n0 + wn + j * 16 + row16;
                if (gc >= N) continue;
                float v = acc[i][j][reg];
                if (bias) v += ldin(bias, gc, f32);
                stval(&C[(long)gr * N + gc], v);
            }
        }
    }
}

// fused 3-way GEMM: blockIdx.z = sel*nbatch + b; sel picks (Bt,C,bias) triple
template <typename OT>
__global__ __launch_bounds__(256) void gemm_mfma3_k(
    const unsigned short* __restrict__ A,
    const unsigned short* Bt0, const unsigned short* Bt1, const unsigned short* Bt2,
    OT* C0, OT* C1, OT* C2,
    const void* bias0, const void* bias1, const void* bias2,
    const int* __restrict__ dflag,
    int M, int N, int K, long sA, long sB, long sC, int nbatch)
{
    __shared__ unsigned short As[128 * LDK];
    __shared__ unsigned short Bs[128 * LDK];
    const int f32 = *dflag;
    const int sel = blockIdx.z / nbatch, b = blockIdx.z % nbatch;
    const unsigned short* Bt = (sel == 0 ? Bt0 : sel == 1 ? Bt1 : Bt2) + (long)b * sB;
    OT* C = (sel == 0 ? C0 : sel == 1 ? C1 : C2) + (long)b * sC;
    const void* bias = sel == 0 ? bias0 : sel == 1 ? bias1 : bias2;
    gemm_mfma_body<OT>(A + (long)b * sA, Bt, C, bias, f32, M, N, K, As, Bs);
}

template <typename OT>
__global__ __launch_bounds__(256) void gemm_mfma_k(
    const unsigned short* __restrict__ A, const unsigned short* __restrict__ Bt,
    OT* __restrict__ C, const void* __restrict__ bias,
    const int* __restrict__ dflag, int M, int N, int K)
{
    __shared__ unsigned short As[128 * LDK];
    __shared__ unsigned short Bs[128 * LDK];
    gemm_mfma_body<OT>(A, Bt, C, bias, *dflag, M, N, K, As, Bs);
}

// ---------- per-(node,r,h) attention dots ----------
__global__ __launch_bounds__(256) void alpha_node0_k(
    const unsigned short* __restrict__ hj, const unsigned short* __restrict__ hi,
    const void* __restrict__ attj, const void* __restrict__ atti,
    const int* __restrict__ dflag,
    float* __restrict__ ajn, float* __restrict__ ain, int Nn)
{
    const int f32 = *dflag;
    int n = (int)((blockIdx.x * 256u + threadIdx.x) >> 6);
    int lane = threadIdx.x & 63;
    if (n >= Nn) return;
    int dd = lane * 4;                 // h = lane>>4
    ushort4 xj = *(const ushort4*)(hj + (long)n * 256 + dd);
    ushort4 xi = *(const ushort4*)(hi + (long)n * 256 + dd);
    float xjf[4] = {b2f(xj.x), b2f(xj.y), b2f(xj.z), b2f(xj.w)};
    float xif[4] = {b2f(xi.x), b2f(xi.y), b2f(xi.z), b2f(xi.w)};
#pragma unroll
    for (int r = 0; r < 5; ++r) {
        long ab = (long)r * 256 + dd;
        float pj = 0.f, pi = 0.f;
#pragma unroll
        for (int j = 0; j < 4; ++j) {
            pj += ldin(attj, ab + j, f32) * xjf[j];
            pi += ldin(atti, ab + j, f32) * xif[j];
        }
#pragma unroll
        for (int m = 1; m < 16; m <<= 1) {
            pj += __shfl_xor(pj, m, 64);
            pi += __shfl_xor(pi, m, 64);
        }
        if ((lane & 15) == 0) {
            ajn[((long)n * 5 + r) * 4 + (lane >> 4)] = pj;
            ain[((long)n * 5 + r) * 4 + (lane >> 4)] = pi;
        }
    }
}

__global__ __launch_bounds__(256) void alpha_node1_k(
    const unsigned short* __restrict__ hj, const unsigned short* __restrict__ hi,
    const void* __restrict__ attj, const void* __restrict__ atti,
    const int* __restrict__ dflag,
    float* __restrict__ ajn, float* __restrict__ ain, int Nn)
{
    const int f32 = *dflag;
    int n = (int)((blockIdx.x * 256u + threadIdx.x) >> 6);
    int lane = threadIdx.x & 63;
    if (n >= Nn) return;
    bool act = lane < 40;
    float xj = act ? b2f(hj[(long)n * 40 + lane]) : 0.f;
    float xi = act ? b2f(hi[(long)n * 40 + lane]) : 0.f;
#pragma unroll
    for (int r = 0; r < 5; ++r) {
        float pj = act ? ldin(attj, (long)r * 40 + lane, f32) * xj : 0.f;
        float pi = act ? ldin(atti, (long)r * 40 + lane, f32) * xi : 0.f;
#pragma unroll
        for (int m = 1; m < 64; m <<= 1) {
            pj += __shfl_xor(pj, m, 64);
            pi += __shfl_xor(pi, m, 64);
        }
        if (lane == 0) {
            ajn[(long)n * 5 + r] = pj;
            ain[(long)n * 5 + r] = pi;
        }
    }
}

// ---------- CSR build: hist + hierarchical scan + scatter ----------
__global__ __launch_bounds__(256) void hist_k(const int* __restrict__ ei, int E, int* __restrict__ cnt)
{
    int e = blockIdx.x * 256 + threadIdx.x;
    if (e < E) atomicAdd(&cnt[ei[E + e]], 1);
}
// per-block 256-elem exclusive scan; block totals to bsum
__global__ __launch_bounds__(256) void scan1_k(
    const int* __restrict__ cnt, int* __restrict__ off, int* __restrict__ bsum, int n)
{
    __shared__ int buf[256];
    int i = blockIdx.x * 256 + threadIdx.x;
    int v = (i < n) ? cnt[i] : 0;
    buf[threadIdx.x] = v;
    __syncthreads();
#pragma unroll
    for (int s = 1; s < 256; s <<= 1) {
        int t = (threadIdx.x >= s) ? buf[threadIdx.x - s] : 0;
        __syncthreads();
        buf[threadIdx.x] += t;
        __syncthreads();
    }
    if (i < n) off[i] = buf[threadIdx.x] - v;
    if (threadIdx.x == 255) bsum[blockIdx.x] = buf[255];
}
// single-block scan of block sums (nb <= 256); writes grand total to *total_dst
__global__ void scan2_k(int* __restrict__ bsum, int nb, int* __restrict__ total_dst)
{
    __shared__ int buf[256];
    int v = (threadIdx.x < nb) ? bsum[threadIdx.x] : 0;
    buf[threadIdx.x] = v;
    __syncthreads();
#pragma unroll
    for (int s = 1; s < 256; s <<= 1) {
        int t = (threadIdx.x >= s) ? buf[threadIdx.x - s] : 0;
        __syncthreads();
        buf[threadIdx.x] += t;
        __syncthreads();
    }
    if (threadIdx.x < nb) bsum[threadIdx.x] = buf[threadIdx.x] - v;  // exclusive
    if (threadIdx.x == 255) *total_dst = buf[255];
}
__global__ __launch_bounds__(256) void scan3_k(
    int* __restrict__ off, int* __restrict__ cursor, const int* __restrict__ bsum, int n)
{
    int i = blockIdx.x * 256 + threadIdx.x;
    if (i < n) {
        int v = off[i] + bsum[blockIdx.x];
        off[i] = v;
        cursor[i] = v;
    }
}
__global__ __launch_bounds__(256) void scatter_k(const int* __restrict__ ei, int E,
                                                 int* __restrict__ cursor, int* __restrict__ elist)
{
    int e = blockIdx.x * 256 + threadIdx.x;
    if (e < E) {
        int p = atomicAdd(&cursor[ei[E + e]], 1);
        elist[p] = e;
    }
}

// ---------- CSR aggregation, layer 0: one wave per tgt; z bf16, no atomics ----------
__global__ __launch_bounds__(256) void aggregate0_k(
    const int* __restrict__ ei, const int* __restrict__ et,
    const int* __restrict__ off, const int* __restrict__ elist,
    const unsigned short* __restrict__ hj,
    const float* __restrict__ ajn, const float* __restrict__ ain,
    unsigned short* __restrict__ z, int Nn, int E)
{
    int tgt = (int)((blockIdx.x * 256u + threadIdx.x) >> 6);
    int lane = threadIdx.x & 63;
    if (tgt >= Nn) return;
    int dd = lane * 4, h = lane >> 4;
    float ainv[5];
#pragma unroll
    for (int r = 0; r < 5; ++r) ainv[r] = ain[((long)tgt * 5 + r) * 4 + h];
    float acc[5][4] = {};
    float den[5] = {};
    int s = off[tgt], epd = off[tgt + 1];
    for (int i = s; i < epd; ++i) {
        int e = elist[i];
        int src = ei[e], r_e = et[e];
        float aj = ajn[((long)src * 5 + r_e) * 4 + h];
        float aiv = ainv[0];
#pragma unroll
        for (int r = 1; r < 5; ++r) aiv = (r_e == r) ? ainv[r] : aiv;
        float al = aj + aiv;
        al = al > 0.f ? al : 0.2f * al;
        al = fminf(al, 60.f);
        float wgt = expf(al);
        ushort4 xj = *(const ushort4*)(hj + (long)src * 256 + dd);
        float x0 = b2f(xj.x), x1 = b2f(xj.y), x2 = b2f(xj.z), x3 = b2f(xj.w);
#pragma unroll
        for (int r = 0; r < 5; ++r) {
            float ws = (r == r_e) ? wgt : 0.f;
            den[r] += ws;
            acc[r][0] += ws * x0; acc[r][1] += ws * x1;
            acc[r][2] += ws * x2; acc[r][3] += ws * x3;
        }
    }
#pragma unroll
    for (int r = 0; r < 5; ++r) {
        float inv = 1.f / fmaxf(den[r], 1e-16f);
        ushort4 o;
        o.x = f2b(acc[r][0] * inv); o.y = f2b(acc[r][1] * inv);
        o.z = f2b(acc[r][2] * inv); o.w = f2b(acc[r][3] * inv);
        *(ushort4*)(z + ((long)r * Nn + tgt) * 256 + dd) = o;
    }
}

// ---------- CSR aggregation, layer 1 (H=1,C=40) ----------
__global__ __launch_bounds__(256) void aggregate1_k(
    const int* __restrict__ ei, const int* __restrict__ et,
    const int* __restrict__ off, const int* __restrict__ elist,
    const unsigned short* __restrict__ hj,
    const float* __restrict__ ajn, const float* __restrict__ ain,
    unsigned short* __restrict__ z, int Nn, int E)
{
    int tgt = (int)((blockIdx.x * 256u + threadIdx.x) >> 6);
    int lane = threadIdx.x & 63;
    if (tgt >= Nn) return;
    bool act = lane < 40;
    float ainv[5];
#pragma unroll
    for (int r = 0; r < 5; ++r) ainv[r] = ain[(long)tgt * 5 + r];
    float acc[5] = {};
    float den[5] = {};
    int s = off[tgt], epd = off[tgt + 1];
    for (int i = s; i < epd; ++i) {
        int e = elist[i];
        int src = ei[e], r_e = et[e];
        float aj = ajn[(long)src * 5 + r_e];
        float aiv = ainv[0];
#pragma unroll
        for (int r = 1; r < 5; ++r) aiv = (r_e == r) ? ainv[r] : aiv;
        float al = aj + aiv;
        al = al > 0.f ? al : 0.2f * al;
        al = fminf(al, 60.f);
        float wgt = expf(al);
        float xj = act ? b2f(hj[(long)src * 40 + lane]) : 0.f;
#pragma unroll
        for (int r = 0; r < 5; ++r) {
            float ws = (r == r_e) ? wgt : 0.f;
            den[r] += ws;
            acc[r] += ws * xj;
        }
    }
    if (act) {
#pragma unroll
        for (int r = 0; r < 5; ++r) {
            float inv = 1.f / fmaxf(den[r], 1e-16f);
            z[((long)r * Nn + tgt) * 40 + lane] = f2b(acc[r] * inv);
        }
    }
}

// ---------- fused relation attention, layer 0 (H=4,C=64): one wave per node ----------
__global__ __launch_bounds__(256) void fused_attn0_k(
    const unsigned short* __restrict__ qb, const unsigned short* __restrict__ kb,
    const unsigned short* __restrict__ vb, const void* __restrict__ wrel,
    unsigned short* __restrict__ x1, int n0, int nloc,
    const int* __restrict__ dflag)
{
    const int f32 = *dflag;
    int nl = (int)((blockIdx.x * 256u + threadIdx.x) >> 6);
    int lane = threadIdx.x & 63;
    if (nl >= nloc) return;
    int n = n0 + nl;
    int dd = lane * 4;
    float qf[5][4], kf[5][4];
#pragma unroll
    for (int r = 0; r < 5; ++r) {
        ushort4 qv = *(const ushort4*)(qb + ((long)r * CHQ + nl) * 256 + dd);
        ushort4 kv = *(const ushort4*)(kb + ((long)r * CHQ + nl) * 256 + dd);
        qf[r][0] = b2f(qv.x); qf[r][1] = b2f(qv.y); qf[r][2] = b2f(qv.z); qf[r][3] = b2f(qv.w);
        kf[r][0] = b2f(kv.x); kf[r][1] = b2f(kv.y); kf[r][2] = b2f(kv.z); kf[r][3] = b2f(kv.w);
    }
    float psi[5][5];
#pragma unroll
    for (int r = 0; r < 5; ++r)
#pragma unroll
        for (int s = 0; s < 5; ++s) {
            float p = qf[r][0] * kf[s][0] + qf[r][1] * kf[s][1] +
                      qf[r][2] * kf[s][2] + qf[r][3] * kf[s][3];
            p += __shfl_xor(p, 1, 64); p += __shfl_xor(p, 2, 64);
            p += __shfl_xor(p, 4, 64); p += __shfl_xor(p, 8, 64);
            psi[r][s] = p;
        }
    float pw[5] = {0.f, 0.f, 0.f, 0.f, 0.f};
#pragma unroll
    for (int r = 0; r < 5; ++r) {
        float rowsum = psi[r][0] + psi[r][1] + psi[r][2] + psi[r][3] + psi[r][4];
        float vals[5], m = NEGBIG;
#pragma unroll
        for (int s = 0; s < 5; ++s) {
            float v = (psi[r][s] == 0.f && rowsum != 0.f) ? NEGBIG : psi[r][s];
            vals[s] = v; m = fmaxf(m, v);
        }
        float es[5], sum = 0.f;
#pragma unroll
        for (int s = 0; s < 5; ++s) { es[s] = expf(vals[s] - m); sum += es[s]; }
        float wr = ldin(wrel, r, f32) / sum;
#pragma unroll
        for (int s = 0; s < 5; ++s) pw[s] += wr * es[s];
    }
    float acc[4] = {0.f, 0.f, 0.f, 0.f};
#pragma unroll
    for (int s = 0; s < 5; ++s) {
        ushort4 vv = *(const ushort4*)(vb + ((long)s * CHQ + nl) * 256 + dd);
        acc[0] += pw[s] * b2f(vv.x); acc[1] += pw[s] * b2f(vv.y);
        acc[2] += pw[s] * b2f(vv.z); acc[3] += pw[s] * b2f(vv.w);
    }
    ushort4* xp = (ushort4*)(x1 + (long)n * 256 + dd);
    ushort4 sv = *xp;
    sv.x = f2b(fmaxf(b2f(sv.x) + acc[0], 0.f));
    sv.y = f2b(fmaxf(b2f(sv.y) + acc[1], 0.f));
    sv.z = f2b(fmaxf(b2f(sv.z) + acc[2], 0.f));
    sv.w = f2b(fmaxf(b2f(sv.w) + acc[3], 0.f));
    *xp = sv;
}

// ---------- fused relation attention, layer 1 (H=1,C=40) + log_softmax -> d_out ----------
__global__ __launch_bounds__(256) void fused_attn1_k(
    const unsigned short* __restrict__ qb, const unsigned short* __restrict__ kb,
    const unsigned short* __restrict__ vb, const void* __restrict__ wrel,
    const float* __restrict__ self1, void* __restrict__ out, int N,
    const int* __restrict__ dflag)
{
    const int f32 = *dflag;
    int n = (int)((blockIdx.x * 256u + threadIdx.x) >> 6);
    int lane = threadIdx.x & 63;
    if (n >= N) return;
    bool act = lane < 40;
    float qf[5], kf[5];
#pragma unroll
    for (int r = 0; r < 5; ++r) {
        long o = ((long)r * N + n) * 40 + lane;
        qf[r] = act ? b2f(qb[o]) : 0.f;
        kf[r] = act ? b2f(kb[o]) : 0.f;
    }
    float psi[5][5];
#pragma unroll
    for (int r = 0; r < 5; ++r)
#pragma unroll
        for (int s = 0; s < 5; ++s) {
            float p = qf[r] * kf[s];
            p += __shfl_xor(p, 1, 64);  p += __shfl_xor(p, 2, 64);
            p += __shfl_xor(p, 4, 64);  p += __shfl_xor(p, 8, 64);
            p += __shfl_xor(p, 16, 64); p += __shfl_xor(p, 32, 64);
            psi[r][s] = p;
        }
    float pw[5] = {0.f, 0.f, 0.f, 0.f, 0.f};
#pragma unroll
    for (int r = 0; r < 5; ++r) {
        float rowsum = psi[r][0] + psi[r][1] + psi[r][2] + psi[r][3] + psi[r][4];
        float vals[5], m = NEGBIG;
#pragma unroll
        for (int s = 0; s < 5; ++s) {
            float v = (psi[r][s] == 0.f && rowsum != 0.f) ? NEGBIG : psi[r][s];
            vals[s] = v; m = fmaxf(m, v);
        }
        float es[5], sum = 0.f;
#pragma unroll
        for (int s = 0; s < 5; ++s) { es[s] = expf(vals[s] - m); sum += es[s]; }
        float wr = ldin(wrel, r, f32) / sum;
#pragma unroll
        for (int s = 0; s < 5; ++s) pw[s] += wr * es[s];
    }
    float val = NEGBIG;
    if (act) {
        float acc = 0.f;
#pragma unroll
        for (int s = 0; s < 5; ++s) acc += pw[s] * b2f(vb[((long)s * N + n) * 40 + lane]);
        val = self1[(long)n * 40 + lane] + acc;
    }
    float m = val;
#pragma unroll
    for (int msk = 1; msk < 64; msk <<= 1) m = fmaxf(m, __shfl_xor(m, msk, 64));
    float e = act ? expf(val - m) : 0.f;
#pragma unroll
    for (int msk = 1; msk < 64; msk <<= 1) e += __shfl_xor(e, msk, 64);
    if (act) {
        float r = val - m - logf(e);
        long oidx = (long)n * 40 + lane;
        if (f32) ((float*)out)[oidx] = r;
        else     ((unsigned short*)out)[oidx] = f2b(r);
    }
}

// ---------- host ----------
extern "C" void kernel_launch(void* const* d_in, const int* in_sizes, int n_in,
                              void* d_out, int out_size, void* d_ws, size_t ws_size,
                              hipStream_t stream)
{
    const int* n_id = (const int*)d_in[0];
    const int* lidx = (const int*)d_in[1];
    const int* ei0  = (const int*)d_in[3];
    const int* et0  = (const int*)d_in[4];
    const int* ei1  = (const int*)d_in[5];
    const int* et1  = (const int*)d_in[6];
    const void* emb = d_in[7];
    const void* Wj0 = d_in[8];  const void* Wi0 = d_in[9];
    const void* aj0 = d_in[10]; const void* ai0 = d_in[11];
    const void* Wq0 = d_in[12]; const void* Wk0 = d_in[13]; const void* Wv0 = d_in[14];
    const void* sw0 = d_in[15]; const void* sb0 = d_in[16]; const void* Wr0 = d_in[17];
    const void* Wj1 = d_in[18]; const void* Wi1 = d_in[19];
    const void* aj1 = d_in[20]; const void* ai1 = d_in[21];
    const void* Wq1 = d_in[22]; const void* Wk1 = d_in[23]; const void* Wv1 = d_in[24];
    const void* sw1 = d_in[25]; const void* sb1 = d_in[26]; const void* Wr1 = d_in[27];
    const int E0 = in_sizes[4], E1 = in_sizes[6];

    // ---- workspace layout, peak ~195 MB ----
    char* w = (char*)d_ws;
    size_t o = 0;
    auto take = [&](size_t b) { char* p = w + o; o += (b + 255) & ~(size_t)255; return p; };
    unsigned short* x30k = (unsigned short*)take((size_t)N1 * IN * 2);
    unsigned short* hj0  = (unsigned short*)take((size_t)N1 * HC0 * 2);
    unsigned short* hi0  = (unsigned short*)take((size_t)N1 * HC0 * 2);
    unsigned short* x1   = (unsigned short*)take((size_t)N1 * HC0 * 2);
    float* ajn0 = (float*)take((size_t)N1 * R * 4 * 4);
    float* ain0 = (float*)take((size_t)N1 * R * 4 * 4);
    int* cnt    = (int*)take((size_t)(N1 + 1) * 4);
    int* off    = (int*)take((size_t)(N1 + 1) * 4);
    int* cursor = (int*)take((size_t)(N1 + 1) * 4);
    int* bsum   = (int*)take(256 * 4);
    int* elist  = (int*)take((size_t)E0 * 4);
    unsigned short* z0 = (unsigned short*)take((size_t)R * N1 * HC0 * 2);
    unsigned short* qc = (unsigned short*)take((size_t)R * CHQ * HC0 * 2);
    unsigned short* kc = (unsigned short*)take((size_t)R * CHQ * HC0 * 2);
    unsigned short* vc = (unsigned short*)take((size_t)R * CHQ * HC0 * 2);
    unsigned short* wjt0 = (unsigned short*)take((size_t)HC0 * IN * 2);
    unsigned short* wit0 = (unsigned short*)take((size_t)HC0 * IN * 2);
    unsigned short* swt0 = (unsigned short*)take((size_t)HC0 * IN * 2);
    unsigned short* wqt0 = (unsigned short*)take((size_t)R * HC0 * HC0 * 2);
    unsigned short* wkt0 = (unsigned short*)take((size_t)R * HC0 * HC0 * 2);
    unsigned short* wvt0 = (unsigned short*)take((size_t)R * HC0 * HC0 * 2);
    unsigned short* wjt1 = (unsigned short*)take((size_t)C1 * HC0 * 2);
    unsigned short* wit1 = (unsigned short*)take((size_t)C1 * HC0 * 2);
    unsigned short* swt1 = (unsigned short*)take((size_t)C1 * HC0 * 2);
    unsigned short* wqt1 = (unsigned short*)take((size_t)R * C1 * C1 * 2);
    unsigned short* wkt1 = (unsigned short*)take((size_t)R * C1 * C1 * 2);
    unsigned short* wvt1 = (unsigned short*)take((size_t)R * C1 * C1 * 2);
    int* dflag = (int*)take(256);
    // layer-1 block overlays [x30k|hj0|hi0] (38.4 MB; all dead before first write)
    size_t o1 = 0;
    auto take1 = [&](size_t b) { char* p = w + o1; o1 += (b + 255) & ~(size_t)255; return p; };
    unsigned short* hj1 = (unsigned short*)take1((size_t)N2 * C1 * 2);
    unsigned short* hi1 = (unsigned short*)take1((size_t)N2 * C1 * 2);
    float* self1 = (float*)take1((size_t)N2 * C1 * 4);
    float* ajn1  = (float*)take1((size_t)N2 * R * 4);
    float* ain1  = (float*)take1((size_t)N2 * R * 4);
    unsigned short* z1  = (unsigned short*)take1((size_t)R * N2 * C1 * 2);
    unsigned short* q1b = (unsigned short*)take1((size_t)R * N2 * C1 * 2);
    unsigned short* k1b = (unsigned short*)take1((size_t)R * N2 * C1 * 2);
    unsigned short* v1b = (unsigned short*)take1((size_t)R * N2 * C1 * 2);

    // ---- dtype flavor detection ----
    detect_k<<<1, 64, 0, stream>>>(emb, dflag);

    // ---- weight transposes (flavored read -> bf16 [N][K]) ----
    {
        long p1 = (long)IN * HC0;
        transpose3_k<<<dim3((unsigned)((p1 + 255) / 256), 3), 256, 0, stream>>>(
            Wj0, Wi0, sw0, wjt0, wit0, swt0, dflag, IN, HC0, p1);
        long p2 = (long)R * HC0 * HC0;
        transpose3_k<<<dim3((unsigned)((p2 + 255) / 256), 3), 256, 0, stream>>>(
            Wq0, Wk0, Wv0, wqt0, wkt0, wvt0, dflag, HC0, HC0, p2);
        long p3 = (long)HC0 * C1;
        transpose3_k<<<dim3((unsigned)((p3 + 255) / 256), 3), 256, 0, stream>>>(
            Wj1, Wi1, sw1, wjt1, wit1, swt1, dflag, HC0, C1, p3);
        long p4 = (long)R * C1 * C1;
        transpose3_k<<<dim3((unsigned)((p4 + 255) / 256), 3), 256, 0, stream>>>(
            Wq1, Wk1, Wv1, wqt1, wkt1, wvt1, dflag, C1, C1, p4);
    }

    // ---- layer 0: features (single fused MFMA launch, sel in {Wj,Wi,sw}) ----
    gather_k<<<(int)(((long)N1 * IN + 255) / 256), 256, 0, stream>>>(n_id, lidx, emb, x30k, N1, dflag);
    gemm_mfma3_k<unsigned short><<<dim3(2, (N1 + 127) / 128, 3), 256, 0, stream>>>(
        x30k, wjt0, wit0, swt0, hj0, hi0, x1, nullptr, nullptr, sb0,
        dflag, N1, HC0, IN, 0, 0, 0, 1);

    // ---- layer 0: alpha precompute + CSR + aggregation ----
    alpha_node0_k<<<(N1 + 3) / 4, 256, 0, stream>>>(hj0, hi0, aj0, ai0, dflag, ajn0, ain0, N1);
    hipMemsetAsync(cnt, 0, (size_t)(N1 + 1) * 4, stream);
    hist_k<<<(E0 + 255) / 256, 256, 0, stream>>>(ei0, E0, cnt);
    {
        int nb = (N1 + 255) / 256;
        scan1_k<<<nb, 256, 0, stream>>>(cnt, off, bsum, N1);
        scan2_k<<<1, 256, 0, stream>>>(bsum, nb, off + N1);
        scan3_k<<<nb, 256, 0, stream>>>(off, cursor, bsum, N1);
    }
    scatter_k<<<(E0 + 255) / 256, 256, 0, stream>>>(ei0, E0, cursor, elist);
    aggregate0_k<<<(N1 + 3) / 4, 256, 0, stream>>>(ei0, et0, off, elist, hj0, ajn0, ain0, z0, N1, E0);

    // ---- layer 0: chunked q/k/v (fused MFMA) + relation attention ----
    for (int c = 0; c < N1 / CHQ; ++c) {
        const unsigned short* zc = z0 + (long)c * CHQ * HC0;
        long sA = (long)N1 * HC0, sB = (long)HC0 * HC0, sC = (long)CHQ * HC0;
        gemm_mfma3_k<unsigned short><<<dim3(2, (CHQ + 127) / 128, 3 * R), 256, 0, stream>>>(
            zc, wqt0, wkt0, wvt0, qc, kc, vc, nullptr, nullptr, nullptr,
            dflag, CHQ, HC0, HC0, sA, sB, sC, R);
        fused_attn0_k<<<(CHQ + 3) / 4, 256, 0, stream>>>(qc, kc, vc, Wr0, x1, c * CHQ, CHQ, dflag);
    }

    // ---- layer 1 ----
    gemm_mfma3_k<unsigned short><<<dim3(1, (N2 + 127) / 128, 2), 256, 0, stream>>>(
        x1, wjt1, wit1, wit1, hj1, hi1, hi1, nullptr, nullptr, nullptr,
        dflag, N2, C1, HC0, 0, 0, 0, 1);
    gemm_mfma_k<float><<<dim3(1, (N2 + 127) / 128, 1), 256, 0, stream>>>(
        x1, swt1, self1, sb1, dflag, N2, C1, HC0);

    alpha_node1_k<<<(N2 + 3) / 4, 256, 0, stream>>>(hj1, hi1, aj1, ai1, dflag, ajn1, ain1, N2);
    hipMemsetAsync(cnt, 0, (size_t)(N2 + 1) * 4, stream);
    hist_k<<<(E1 + 255) / 256, 256, 0, stream>>>(ei1, E1, cnt);
    {
        int nb = (N2 + 255) / 256;
        scan1_k<<<nb, 256, 0, stream>>>(cnt, off, bsum, N2);
        scan2_k<<<1, 256, 0, stream>>>(bsum, nb, off + N2);
        scan3_k<<<nb, 256, 0, stream>>>(off, cursor, bsum, N2);
    }
    scatter_k<<<(E1 + 255) / 256, 256, 0, stream>>>(ei1, E1, cursor, elist);
    aggregate1_k<<<(N2 + 3) / 4, 256, 0, stream>>>(ei1, et1, off, elist, hj1, ajn1, ain1, z1, N2, E1);

    {
        long sA = (long)N2 * C1, sB = (long)C1 * C1, sC = (long)N2 * C1;
        gemm_mfma3_k<unsigned short><<<dim3(1, (N2 + 127) / 128, 3 * R), 256, 0, stream>>>(
            z1, wqt1, wkt1, wvt1, q1b, k1b, v1b, nullptr, nullptr, nullptr,
            dflag, N2, C1, C1, sA, sB, sC, R);
    }
    fused_attn1_k<<<(N2 + 3) / 4, 256, 0, stream>>>(q1b, k1b, v1b, Wr1, self1, d_out, N2, dflag);
}

// Round 7
// 756.908 us; speedup vs baseline: 5.8778x; 1.0936x over previous
//
#include <hip/hip_runtime.h>
#include <hip/hip_bf16.h>

#define DI __device__ __forceinline__

// ---------- bf16 helpers (raw ushort bits) ----------
DI float b2f(unsigned short u) {
    union { unsigned int i; float f; } x; x.i = ((unsigned int)u) << 16; return x.f;
}
DI unsigned short f2b(float f) {
    union { float f; unsigned int i; } x; x.f = f;
    unsigned int r = x.i + 0x7fff + ((x.i >> 16) & 1);  // RNE
    return (unsigned short)(r >> 16);
}
// flavor-aware input load: f32!=0 -> fp32 array, else bf16 array
DI float ldin(const void* p, long i, int f32) {
    return f32 ? ((const float*)p)[i] : b2f(((const unsigned short*)p)[i]);
}
DI void stval(float* p, float v) { *p = v; }
DI void stval(unsigned short* p, float v) { *p = f2b(v); }

// ---------- constants ----------
static constexpr int N1 = 30000, N2 = 15000, R = 5;
static constexpr int IN = 128, HC0 = 256, C1 = 40;
static constexpr int CHQ = 7500;           // layer-0 qkv/attn chunk (4 chunks)
static constexpr float NEGBIG = -1e30f;    // finite "-inf" (NaN-proof masking)
static constexpr int LDK = 64;             // LDS K-stride, unpadded (m97 pattern)

typedef short bf16x8 __attribute__((ext_vector_type(8)));
typedef float f32x4 __attribute__((ext_vector_type(4)));

// ---------- dtype flavor detection (fp32 read as bf16 -> huge/NaN exponents) ----------
__global__ void detect_k(const void* emb, int* flag)
{
    int lane = threadIdx.x;   // 64 threads
    int bad = 0;
    for (int j = 0; j < 4; ++j) {
        float f = b2f(((const unsigned short*)emb)[lane * 4 + j]);
        if (!(fabsf(f) < 1e8f)) bad = 1;   // catches NaN too
    }
    unsigned long long anybad = __ballot(bad != 0);
    if (lane == 0) *flag = (anybad != 0ull) ? 1 : 0;
}

// ---------- weight transpose: dst[b][n][k] = bf16(src[b][k][n]), 3 tensors ----------
__global__ __launch_bounds__(256) void transpose3_k(
    const void* s0, const void* s1, const void* s2,
    unsigned short* d0, unsigned short* d1, unsigned short* d2,
    const int* __restrict__ dflag, int K, int N, long per)
{
    const int f32 = *dflag;
    long t = (long)blockIdx.x * 256 + threadIdx.x;
    if (t >= per) return;
    const void* s = blockIdx.y == 0 ? s0 : blockIdx.y == 1 ? s1 : s2;
    unsigned short* d = blockIdx.y == 0 ? d0 : blockIdx.y == 1 ? d1 : d2;
    long kn = (long)K * N;
    long b = t / kn, rem = t % kn;
    long k = rem / N, n = rem % N;          // t fastest over n -> coalesced read
    d[(b * N + n) * K + k] = f2b(ldin(s, t, f32));
}

// ---------- build alpha-GEMM B^T matrices ----------
// A0j[j=r*4+h][k] = attj0[r,h,c] if k==h*64+c else 0   (20 x 256)
// A1j[j=r][k=c]   = attj1[r,c]                          (5 x 40)
__global__ __launch_bounds__(256) void att_build_k(
    const void* aj0, const void* ai0, const void* aj1, const void* ai1,
    unsigned short* A0j, unsigned short* A0i, unsigned short* A1j, unsigned short* A1i,
    const int* __restrict__ dflag)
{
    const int f32 = *dflag;
    int t = blockIdx.x * 256 + threadIdx.x;
    if (t < 20 * 256) {
        int j = t >> 8, k = t & 255;
        int h = j & 3, r = j >> 2;
        bool on = (k >> 6) == h;
        A0j[t] = f2b(on ? ldin(aj0, r * 256 + k, f32) : 0.f);
        A0i[t] = f2b(on ? ldin(ai0, r * 256 + k, f32) : 0.f);
    }
    if (t < 5 * 40) {
        A1j[t] = f2b(ldin(aj1, t, f32));
        A1i[t] = f2b(ldin(ai1, t, f32));
    }
}

// ---------- gather x[:N1] = bf16(emb[lidx[n_id[n]]]) ----------
__global__ __launch_bounds__(256) void gather_k(
    const int* __restrict__ n_id, const int* __restrict__ lidx,
    const void* __restrict__ emb, unsigned short* __restrict__ x, int rows,
    const int* __restrict__ dflag)
{
    const int f32 = *dflag;
    long t = (long)blockIdx.x * 256 + threadIdx.x;
    long n = t >> 7, d = t & 127;
    if (n >= rows) return;
    long row = lidx[n_id[n]];
    x[n * IN + d] = f2b(ldin(emb, row * IN + d, f32));
}

// ---------- MFMA GEMM core: 128x128 tile, 4 waves, BK=64, 16x16x32 bf16 ----------
// Fast staging: global_load_lds width=16 (m97). LDS dst is wave-uniform base +
// lane*16B; lane l lands at (l>>3)*64+(l&7)*8 shorts == row-major [8rows][64].
DI void stage_fast(const unsigned short* __restrict__ G, int K,
                   unsigned short* S, int wave, int lane)
{
#pragma unroll
    for (int t = 0; t < 4; ++t) {
        int row = t * 32 + wave * 8 + (lane >> 3);
        const unsigned short* src = G + (long)row * K + (lane & 7) * 8;
        unsigned short* dst = S + (t * 32 + wave * 8) * LDK;   // wave-uniform
        __builtin_amdgcn_global_load_lds(
            (const __attribute__((address_space(1))) unsigned int*)src,
            (__attribute__((address_space(3))) unsigned int*)dst, 16, 0, 0);
    }
}
// Slow staging (boundary rows / ragged K): guarded, zero-filled
DI void stage_slow(const unsigned short* __restrict__ G, int rows, int K,
                   int r0, int k0, unsigned short* S, int tid)
{
    const int sr = tid >> 1, sq = (tid & 1) * 32;
    unsigned short* dst = S + sr * LDK + sq;
    const unsigned short* g = G + (long)(r0 + sr) * K + k0 + sq;
    const bool rowok = (r0 + sr) < rows;
    if (rowok && (k0 + sq + 32) <= K) {
        const uint4* gv = (const uint4*)g;
        uint4 a = gv[0], b = gv[1], c = gv[2], d = gv[3];
        *(uint4*)(dst) = a; *(uint4*)(dst + 8) = b;
        *(uint4*)(dst + 16) = c; *(uint4*)(dst + 24) = d;
    } else {
#pragma unroll 8
        for (int j = 0; j < 32; ++j) {
            int k = k0 + sq + j;
            dst[j] = (rowok && k < K) ? g[j] : (unsigned short)0;
        }
    }
}

template <typename OT>
DI void gemm_mfma_body(
    const unsigned short* __restrict__ A, const unsigned short* __restrict__ Bt,
    OT* __restrict__ C, const void* __restrict__ bias, int f32,
    int M, int N, int K, unsigned short* As, unsigned short* Bs)
{
    const int tid = threadIdx.x;
    const int m0 = blockIdx.y * 128, n0 = blockIdx.x * 128;
    const int lane = tid & 63, wave = tid >> 6;
    const int wm = (wave & 1) * 64, wn = (wave >> 1) * 64;
    const int row16 = lane & 15, quad = lane >> 4;
    const bool kfull = (K & 63) == 0;
    const bool fastA = kfull && (m0 + 128 <= M);
    const bool fastB = kfull && (n0 + 128 <= N);
    f32x4 acc[4][4];
#pragma unroll
    for (int i = 0; i < 4; ++i)
#pragma unroll
        for (int j = 0; j < 4; ++j) acc[i][j] = {0.f, 0.f, 0.f, 0.f};

    for (int k0 = 0; k0 < K; k0 += 64) {
        if (fastA) stage_fast(A + (long)m0 * K + k0, K, As, wave, lane);
        else       stage_slow(A, M, K, m0, k0, As, tid);
        if (fastB) stage_fast(Bt + (long)n0 * K + k0, K, Bs, wave, lane);
        else       stage_slow(Bt, N, K, n0, k0, Bs, tid);
        __syncthreads();
#pragma unroll
        for (int ks = 0; ks < 64; ks += 32) {
            bf16x8 af[4], bfr[4];
#pragma unroll
            for (int i = 0; i < 4; ++i)
                af[i] = *(const bf16x8*)(As + (wm + i * 16 + row16) * LDK + ks + quad * 8);
#pragma unroll
            for (int j = 0; j < 4; ++j)
                bfr[j] = *(const bf16x8*)(Bs + (wn + j * 16 + row16) * LDK + ks + quad * 8);
#pragma unroll
            for (int i = 0; i < 4; ++i)
#pragma unroll
                for (int j = 0; j < 4; ++j)
                    acc[i][j] = __builtin_amdgcn_mfma_f32_16x16x32_bf16(
                        af[i], bfr[j], acc[i][j], 0, 0, 0);
        }
        __syncthreads();
    }
#pragma unroll
    for (int i = 0; i < 4; ++i) {
#pragma unroll
        for (int reg = 0; reg < 4; ++reg) {
            const int gr = m0 + wm + i * 16 + quad * 4 + reg;
            if (gr >= M) continue;
#pragma unroll
            for (int j = 0; j < 4; ++j) {
                const int gc = n0 + wn + j * 16 + row16;
                if (gc >= N) continue;
                float v = acc[i][j][reg];
                if (bias) v += ldin(bias, gc, f32);
                stval(&C[(long)gr * N + gc], v);
            }
        }
    }
}

// fused 3-way GEMM: blockIdx.z = sel*nbatch + b; sel picks (A,Bt,C,bias) quad
template <typename OT>
__global__ __launch_bounds__(256) void gemm_mfma3_k(
    const unsigned short* A0, const unsigned short* A1, const unsigned short* A2,
    const unsigned short* Bt0, const unsigned short* Bt1, const unsigned short* Bt2,
    OT* C0, OT* C1, OT* C2,
    const void* bias0, const void* bias1, const void* bias2,
    const int* __restrict__ dflag,
    int M, int N, int K, long sA, long sB, long sC, int nbatch)
{
    __shared__ unsigned short As[128 * LDK];
    __shared__ unsigned short Bs[128 * LDK];
    const int f32 = *dflag;
    const int sel = blockIdx.z / nbatch, b = blockIdx.z % nbatch;
    const unsigned short* A  = (sel == 0 ? A0 : sel == 1 ? A1 : A2) + (long)b * sA;
    const unsigned short* Bt = (sel == 0 ? Bt0 : sel == 1 ? Bt1 : Bt2) + (long)b * sB;
    OT* C = (sel == 0 ? C0 : sel == 1 ? C1 : C2) + (long)b * sC;
    const void* bias = sel == 0 ? bias0 : sel == 1 ? bias1 : bias2;
    gemm_mfma_body<OT>(A, Bt, C, bias, f32, M, N, K, As, Bs);
}

// ---------- CSR build: hist + hierarchical scan + weighted scatter ----------
__global__ __launch_bounds__(256) void hist_k(const int* __restrict__ ei, int E, int* __restrict__ cnt)
{
    int e = blockIdx.x * 256 + threadIdx.x;
    if (e < E) atomicAdd(&cnt[ei[E + e]], 1);
}
__global__ __launch_bounds__(256) void scan1_k(
    const int* __restrict__ cnt, int* __restrict__ off, int* __restrict__ bsum, int n)
{
    __shared__ int buf[256];
    int i = blockIdx.x * 256 + threadIdx.x;
    int v = (i < n) ? cnt[i] : 0;
    buf[threadIdx.x] = v;
    __syncthreads();
#pragma unroll
    for (int s = 1; s < 256; s <<= 1) {
        int t = (threadIdx.x >= s) ? buf[threadIdx.x - s] : 0;
        __syncthreads();
        buf[threadIdx.x] += t;
        __syncthreads();
    }
    if (i < n) off[i] = buf[threadIdx.x] - v;
    if (threadIdx.x == 255) bsum[blockIdx.x] = buf[255];
}
__global__ void scan2_k(int* __restrict__ bsum, int nb, int* __restrict__ total_dst)
{
    __shared__ int buf[256];
    int v = (threadIdx.x < nb) ? bsum[threadIdx.x] : 0;
    buf[threadIdx.x] = v;
    __syncthreads();
#pragma unroll
    for (int s = 1; s < 256; s <<= 1) {
        int t = (threadIdx.x >= s) ? buf[threadIdx.x - s] : 0;
        __syncthreads();
        buf[threadIdx.x] += t;
        __syncthreads();
    }
    if (threadIdx.x < nb) bsum[threadIdx.x] = buf[threadIdx.x] - v;  // exclusive
    if (threadIdx.x == 255) *total_dst = buf[255];
}
__global__ __launch_bounds__(256) void scan3_k(
    int* __restrict__ off, int* __restrict__ cursor, const int* __restrict__ bsum, int n)
{
    int i = blockIdx.x * 256 + threadIdx.x;
    if (i < n) {
        int v = off[i] + bsum[blockIdx.x];
        off[i] = v;
        cursor[i] = v;
    }
}
// scatter + per-edge softmax weights (4 heads), emitting tgt-sorted streams
__global__ __launch_bounds__(256) void scatter0_k(
    const int* __restrict__ ei, const int* __restrict__ et, int E,
    int* __restrict__ cursor,
    const float* __restrict__ ajn, const float* __restrict__ ain,
    int* __restrict__ src_s, int* __restrict__ rt_s, float* __restrict__ w4_s)
{
    int e = blockIdx.x * 256 + threadIdx.x;
    if (e >= E) return;
    int src = ei[e], tgt = ei[E + e], r = et[e];
    int p = atomicAdd(&cursor[tgt], 1);
    src_s[p] = src; rt_s[p] = r;
    float4 a = *(const float4*)(ajn + (long)src * 20 + r * 4);
    float4 b = *(const float4*)(ain + (long)tgt * 20 + r * 4);
    float4 w;
    float s0 = a.x + b.x, s1 = a.y + b.y, s2 = a.z + b.z, s3 = a.w + b.w;
    s0 = s0 > 0.f ? s0 : 0.2f * s0;  s1 = s1 > 0.f ? s1 : 0.2f * s1;
    s2 = s2 > 0.f ? s2 : 0.2f * s2;  s3 = s3 > 0.f ? s3 : 0.2f * s3;
    w.x = expf(fminf(s0, 60.f)); w.y = expf(fminf(s1, 60.f));
    w.z = expf(fminf(s2, 60.f)); w.w = expf(fminf(s3, 60.f));
    *(float4*)(w4_s + (long)p * 4) = w;
}
__global__ __launch_bounds__(256) void scatter1_k(
    const int* __restrict__ ei, const int* __restrict__ et, int E,
    int* __restrict__ cursor,
    const float* __restrict__ ajn, const float* __restrict__ ain,
    int* __restrict__ src_s, int* __restrict__ rt_s, float* __restrict__ w_s)
{
    int e = blockIdx.x * 256 + threadIdx.x;
    if (e >= E) return;
    int src = ei[e], tgt = ei[E + e], r = et[e];
    int p = atomicAdd(&cursor[tgt], 1);
    src_s[p] = src; rt_s[p] = r;
    float s = ajn[(long)src * 5 + r] + ain[(long)tgt * 5 + r];
    s = s > 0.f ? s : 0.2f * s;
    w_s[p] = expf(fminf(s, 60.f));
}

// ---------- CSR aggregation, layer 0: one wave per tgt, sequential streams ----------
__global__ __launch_bounds__(256) void aggregate0_k(
    const int* __restrict__ src_s, const int* __restrict__ rt_s,
    const float* __restrict__ w4_s, const int* __restrict__ off,
    const unsigned short* __restrict__ hj,
    unsigned short* __restrict__ z, int Nn)
{
    int tgt = (int)((blockIdx.x * 256u + threadIdx.x) >> 6);
    int lane = threadIdx.x & 63;
    if (tgt >= Nn) return;
    int dd = lane * 4, h = lane >> 4;
    float acc[5][4] = {};
    float den[5] = {};
    int s = off[tgt], epd = off[tgt + 1];
    for (int i = s; i < epd; ++i) {
        int src = src_s[i];
        int r_e = rt_s[i];
        float wgt = w4_s[(long)i * 4 + h];
        ushort4 xj = *(const ushort4*)(hj + (long)src * 256 + dd);
        float x0 = b2f(xj.x), x1 = b2f(xj.y), x2 = b2f(xj.z), x3 = b2f(xj.w);
#pragma unroll
        for (int r = 0; r < 5; ++r) {
            float ws = (r == r_e) ? wgt : 0.f;
            den[r] += ws;
            acc[r][0] += ws * x0; acc[r][1] += ws * x1;
            acc[r][2] += ws * x2; acc[r][3] += ws * x3;
        }
    }
#pragma unroll
    for (int r = 0; r < 5; ++r) {
        float inv = 1.f / fmaxf(den[r], 1e-16f);
        ushort4 o;
        o.x = f2b(acc[r][0] * inv); o.y = f2b(acc[r][1] * inv);
        o.z = f2b(acc[r][2] * inv); o.w = f2b(acc[r][3] * inv);
        *(ushort4*)(z + ((long)r * Nn + tgt) * 256 + dd) = o;
    }
}

// ---------- CSR aggregation, layer 1 (H=1,C=40) ----------
__global__ __launch_bounds__(256) void aggregate1_k(
    const int* __restrict__ src_s, const int* __restrict__ rt_s,
    const float* __restrict__ w_s, const int* __restrict__ off,
    const unsigned short* __restrict__ hj,
    unsigned short* __restrict__ z, int Nn)
{
    int tgt = (int)((blockIdx.x * 256u + threadIdx.x) >> 6);
    int lane = threadIdx.x & 63;
    if (tgt >= Nn) return;
    bool act = lane < 40;
    float acc[5] = {};
    float den[5] = {};
    int s = off[tgt], epd = off[tgt + 1];
    for (int i = s; i < epd; ++i) {
        int src = src_s[i];
        int r_e = rt_s[i];
        float wgt = w_s[i];
        float xj = act ? b2f(hj[(long)src * 40 + lane]) : 0.f;
#pragma unroll
        for (int r = 0; r < 5; ++r) {
            float ws = (r == r_e) ? wgt : 0.f;
            den[r] += ws;
            acc[r] += ws * xj;
        }
    }
    if (act) {
#pragma unroll
        for (int r = 0; r < 5; ++r) {
            float inv = 1.f / fmaxf(den[r], 1e-16f);
            z[((long)r * Nn + tgt) * 40 + lane] = f2b(acc[r] * inv);
        }
    }
}

// ---------- fused relation attention, layer 0 (H=4,C=64): one wave per node ----------
__global__ __launch_bounds__(256) void fused_attn0_k(
    const unsigned short* __restrict__ qb, const unsigned short* __restrict__ kb,
    const unsigned short* __restrict__ vb, const void* __restrict__ wrel,
    unsigned short* __restrict__ x1, int n0, int nloc,
    const int* __restrict__ dflag)
{
    const int f32 = *dflag;
    int nl = (int)((blockIdx.x * 256u + threadIdx.x) >> 6);
    int lane = threadIdx.x & 63;
    if (nl >= nloc) return;
    int n = n0 + nl;
    int dd = lane * 4;
    float qf[5][4], kf[5][4];
#pragma unroll
    for (int r = 0; r < 5; ++r) {
        ushort4 qv = *(const ushort4*)(qb + ((long)r * CHQ + nl) * 256 + dd);
        ushort4 kv = *(const ushort4*)(kb + ((long)r * CHQ + nl) * 256 + dd);
        qf[r][0] = b2f(qv.x); qf[r][1] = b2f(qv.y); qf[r][2] = b2f(qv.z); qf[r][3] = b2f(qv.w);
        kf[r][0] = b2f(kv.x); kf[r][1] = b2f(kv.y); kf[r][2] = b2f(kv.z); kf[r][3] = b2f(kv.w);
    }
    float psi[5][5];
#pragma unroll
    for (int r = 0; r < 5; ++r)
#pragma unroll
        for (int s = 0; s < 5; ++s) {
            float p = qf[r][0] * kf[s][0] + qf[r][1] * kf[s][1] +
                      qf[r][2] * kf[s][2] + qf[r][3] * kf[s][3];
            p += __shfl_xor(p, 1, 64); p += __shfl_xor(p, 2, 64);
            p += __shfl_xor(p, 4, 64); p += __shfl_xor(p, 8, 64);
            psi[r][s] = p;
        }
    float pw[5] = {0.f, 0.f, 0.f, 0.f, 0.f};
#pragma unroll
    for (int r = 0; r < 5; ++r) {
        float rowsum = psi[r][0] + psi[r][1] + psi[r][2] + psi[r][3] + psi[r][4];
        float vals[5], m = NEGBIG;
#pragma unroll
        for (int s = 0; s < 5; ++s) {
            float v = (psi[r][s] == 0.f && rowsum != 0.f) ? NEGBIG : psi[r][s];
            vals[s] = v; m = fmaxf(m, v);
        }
        float es[5], sum = 0.f;
#pragma unroll
        for (int s = 0; s < 5; ++s) { es[s] = expf(vals[s] - m); sum += es[s]; }
        float wr = ldin(wrel, r, f32) / sum;
#pragma unroll
        for (int s = 0; s < 5; ++s) pw[s] += wr * es[s];
    }
    float acc[4] = {0.f, 0.f, 0.f, 0.f};
#pragma unroll
    for (int s = 0; s < 5; ++s) {
        ushort4 vv = *(const ushort4*)(vb + ((long)s * CHQ + nl) * 256 + dd);
        acc[0] += pw[s] * b2f(vv.x); acc[1] += pw[s] * b2f(vv.y);
        acc[2] += pw[s] * b2f(vv.z); acc[3] += pw[s] * b2f(vv.w);
    }
    ushort4* xp = (ushort4*)(x1 + (long)n * 256 + dd);
    ushort4 sv = *xp;
    sv.x = f2b(fmaxf(b2f(sv.x) + acc[0], 0.f));
    sv.y = f2b(fmaxf(b2f(sv.y) + acc[1], 0.f));
    sv.z = f2b(fmaxf(b2f(sv.z) + acc[2], 0.f));
    sv.w = f2b(fmaxf(b2f(sv.w) + acc[3], 0.f));
    *xp = sv;
}

// ---------- fused relation attention, layer 1 (H=1,C=40) + log_softmax -> d_out ----------
__global__ __launch_bounds__(256) void fused_attn1_k(
    const unsigned short* __restrict__ qb, const unsigned short* __restrict__ kb,
    const unsigned short* __restrict__ vb, const void* __restrict__ wrel,
    const unsigned short* __restrict__ self1, void* __restrict__ out, int N,
    const int* __restrict__ dflag)
{
    const int f32 = *dflag;
    int n = (int)((blockIdx.x * 256u + threadIdx.x) >> 6);
    int lane = threadIdx.x & 63;
    if (n >= N) return;
    bool act = lane < 40;
    float qf[5], kf[5];
#pragma unroll
    for (int r = 0; r < 5; ++r) {
        long o = ((long)r * N + n) * 40 + lane;
        qf[r] = act ? b2f(qb[o]) : 0.f;
        kf[r] = act ? b2f(kb[o]) : 0.f;
    }
    float psi[5][5];
#pragma unroll
    for (int r = 0; r < 5; ++r)
#pragma unroll
        for (int s = 0; s < 5; ++s) {
            float p = qf[r] * kf[s];
            p += __shfl_xor(p, 1, 64);  p += __shfl_xor(p, 2, 64);
            p += __shfl_xor(p, 4, 64);  p += __shfl_xor(p, 8, 64);
            p += __shfl_xor(p, 16, 64); p += __shfl_xor(p, 32, 64);
            psi[r][s] = p;
        }
    float pw[5] = {0.f, 0.f, 0.f, 0.f, 0.f};
#pragma unroll
    for (int r = 0; r < 5; ++r) {
        float rowsum = psi[r][0] + psi[r][1] + psi[r][2] + psi[r][3] + psi[r][4];
        float vals[5], m = NEGBIG;
#pragma unroll
        for (int s = 0; s < 5; ++s) {
            float v = (psi[r][s] == 0.f && rowsum != 0.f) ? NEGBIG : psi[r][s];
            vals[s] = v; m = fmaxf(m, v);
        }
        float es[5], sum = 0.f;
#pragma unroll
        for (int s = 0; s < 5; ++s) { es[s] = expf(vals[s] - m); sum += es[s]; }
        float wr = ldin(wrel, r, f32) / sum;
#pragma unroll
        for (int s = 0; s < 5; ++s) pw[s] += wr * es[s];
    }
    float val = NEGBIG;
    if (act) {
        float acc = 0.f;
#pragma unroll
        for (int s = 0; s < 5; ++s) acc += pw[s] * b2f(vb[((long)s * N + n) * 40 + lane]);
        val = b2f(self1[(long)n * 40 + lane]) + acc;
    }
    float m = val;
#pragma unroll
    for (int msk = 1; msk < 64; msk <<= 1) m = fmaxf(m, __shfl_xor(m, msk, 64));
    float e = act ? expf(val - m) : 0.f;
#pragma unroll
    for (int msk = 1; msk < 64; msk <<= 1) e += __shfl_xor(e, msk, 64);
    if (act) {
        float r = val - m - logf(e);
        long oidx = (long)n * 40 + lane;
        if (f32) ((float*)out)[oidx] = r;
        else     ((unsigned short*)out)[oidx] = f2b(r);
    }
}

// ---------- host ----------
extern "C" void kernel_launch(void* const* d_in, const int* in_sizes, int n_in,
                              void* d_out, int out_size, void* d_ws, size_t ws_size,
                              hipStream_t stream)
{
    const int* n_id = (const int*)d_in[0];
    const int* lidx = (const int*)d_in[1];
    const int* ei0  = (const int*)d_in[3];
    const int* et0  = (const int*)d_in[4];
    const int* ei1  = (const int*)d_in[5];
    const int* et1  = (const int*)d_in[6];
    const void* emb = d_in[7];
    const void* Wj0 = d_in[8];  const void* Wi0 = d_in[9];
    const void* aj0 = d_in[10]; const void* ai0 = d_in[11];
    const void* Wq0 = d_in[12]; const void* Wk0 = d_in[13]; const void* Wv0 = d_in[14];
    const void* sw0 = d_in[15]; const void* sb0 = d_in[16]; const void* Wr0 = d_in[17];
    const void* Wj1 = d_in[18]; const void* Wi1 = d_in[19];
    const void* aj1 = d_in[20]; const void* ai1 = d_in[21];
    const void* Wq1 = d_in[22]; const void* Wk1 = d_in[23]; const void* Wv1 = d_in[24];
    const void* sw1 = d_in[25]; const void* sb1 = d_in[26]; const void* Wr1 = d_in[27];
    const int E0 = in_sizes[4], E1 = in_sizes[6];

    // ---- workspace: overlay region Q (40MB) + persistent (~131MB) = ~171MB ----
    char* w = (char*)d_ws;
    const size_t QSZ = 40u * 1024 * 1024;
    // Q phase 1: x30k | hj0 | hi0
    unsigned short* x30k = (unsigned short*)(w);
    unsigned short* hj0  = (unsigned short*)(w + ((size_t)N1 * IN * 2 + 255 & ~(size_t)255));
    unsigned short* hi0  = (unsigned short*)((char*)hj0 + ((size_t)N1 * HC0 * 2 + 255 & ~(size_t)255));
    // Q phase 2 (after aggregate0): qc | kc
    unsigned short* qc = (unsigned short*)(w);
    unsigned short* kc = (unsigned short*)(w + ((size_t)R * CHQ * HC0 * 2 + 255 & ~(size_t)255));
    // Q phase 3 (after attn0 loop): layer-1 block
    size_t o1 = 0;
    auto take1 = [&](size_t b) { char* p = w + o1; o1 += (b + 255) & ~(size_t)255; return p; };
    unsigned short* hj1   = (unsigned short*)take1((size_t)N2 * C1 * 2);
    unsigned short* hi1   = (unsigned short*)take1((size_t)N2 * C1 * 2);
    unsigned short* self1 = (unsigned short*)take1((size_t)N2 * C1 * 2);
    float* ajn1 = (float*)take1((size_t)N2 * R * 4);
    float* ain1 = (float*)take1((size_t)N2 * R * 4);
    unsigned short* z1  = (unsigned short*)take1((size_t)R * N2 * C1 * 2);
    unsigned short* q1b = (unsigned short*)take1((size_t)R * N2 * C1 * 2);
    unsigned short* k1b = (unsigned short*)take1((size_t)R * N2 * C1 * 2);
    unsigned short* v1b = (unsigned short*)take1((size_t)R * N2 * C1 * 2);
    // persistent
    size_t o = QSZ;
    auto take = [&](size_t b) { char* p = w + o; o += (b + 255) & ~(size_t)255; return p; };
    unsigned short* z0 = (unsigned short*)take((size_t)R * N1 * HC0 * 2);
    unsigned short* vc = (unsigned short*)take((size_t)R * CHQ * HC0 * 2);
    unsigned short* x1 = (unsigned short*)take((size_t)N1 * HC0 * 2);
    float* ajn0 = (float*)take((size_t)N1 * R * 4 * 4);
    float* ain0 = (float*)take((size_t)N1 * R * 4 * 4);
    int* cnt    = (int*)take((size_t)(N1 + 1) * 4);
    int* off    = (int*)take((size_t)(N1 + 1) * 4);
    int* cursor = (int*)take((size_t)(N1 + 1) * 4);
    int* bsum   = (int*)take(256 * 4);
    int* src_s  = (int*)take((size_t)E0 * 4);
    int* rt_s   = (int*)take((size_t)E0 * 4);
    float* w4_s = (float*)take((size_t)E0 * 4 * 4);
    unsigned short* wjt0 = (unsigned short*)take((size_t)HC0 * IN * 2);
    unsigned short* wit0 = (unsigned short*)take((size_t)HC0 * IN * 2);
    unsigned short* swt0 = (unsigned short*)take((size_t)HC0 * IN * 2);
    unsigned short* wqt0 = (unsigned short*)take((size_t)R * HC0 * HC0 * 2);
    unsigned short* wkt0 = (unsigned short*)take((size_t)R * HC0 * HC0 * 2);
    unsigned short* wvt0 = (unsigned short*)take((size_t)R * HC0 * HC0 * 2);
    unsigned short* wjt1 = (unsigned short*)take((size_t)C1 * HC0 * 2);
    unsigned short* wit1 = (unsigned short*)take((size_t)C1 * HC0 * 2);
    unsigned short* swt1 = (unsigned short*)take((size_t)C1 * HC0 * 2);
    unsigned short* wqt1 = (unsigned short*)take((size_t)R * C1 * C1 * 2);
    unsigned short* wkt1 = (unsigned short*)take((size_t)R * C1 * C1 * 2);
    unsigned short* wvt1 = (unsigned short*)take((size_t)R * C1 * C1 * 2);
    unsigned short* atA0j = (unsigned short*)take(20 * 256 * 2);
    unsigned short* atA0i = (unsigned short*)take(20 * 256 * 2);
    unsigned short* atA1j = (unsigned short*)take(5 * 40 * 2);
    unsigned short* atA1i = (unsigned short*)take(5 * 40 * 2);
    int* dflag = (int*)take(256);

    // ---- dtype flavor detection ----
    detect_k<<<1, 64, 0, stream>>>(emb, dflag);

    // ---- weight prep ----
    {
        long p1 = (long)IN * HC0;
        transpose3_k<<<dim3((unsigned)((p1 + 255) / 256), 3), 256, 0, stream>>>(
            Wj0, Wi0, sw0, wjt0, wit0, swt0, dflag, IN, HC0, p1);
        long p2 = (long)R * HC0 * HC0;
        transpose3_k<<<dim3((unsigned)((p2 + 255) / 256), 3), 256, 0, stream>>>(
            Wq0, Wk0, Wv0, wqt0, wkt0, wvt0, dflag, HC0, HC0, p2);
        long p3 = (long)HC0 * C1;
        transpose3_k<<<dim3((unsigned)((p3 + 255) / 256), 3), 256, 0, stream>>>(
            Wj1, Wi1, sw1, wjt1, wit1, swt1, dflag, HC0, C1, p3);
        long p4 = (long)R * C1 * C1;
        transpose3_k<<<dim3((unsigned)((p4 + 255) / 256), 3), 256, 0, stream>>>(
            Wq1, Wk1, Wv1, wqt1, wkt1, wvt1, dflag, C1, C1, p4);
        att_build_k<<<20, 256, 0, stream>>>(aj0, ai0, aj1, ai1, atA0j, atA0i, atA1j, atA1i, dflag);
    }

    // ---- layer 0: features + alpha (both MFMA) ----
    gather_k<<<(int)(((long)N1 * IN + 255) / 256), 256, 0, stream>>>(n_id, lidx, emb, x30k, N1, dflag);
    gemm_mfma3_k<unsigned short><<<dim3(2, (N1 + 127) / 128, 3), 256, 0, stream>>>(
        x30k, x30k, x30k, wjt0, wit0, swt0, hj0, hi0, x1, nullptr, nullptr, sb0,
        dflag, N1, HC0, IN, 0, 0, 0, 1);
    gemm_mfma3_k<float><<<dim3(1, (N1 + 127) / 128, 2), 256, 0, stream>>>(
        hj0, hi0, hi0, atA0j, atA0i, atA0i, ajn0, ain0, ain0, nullptr, nullptr, nullptr,
        dflag, N1, 20, HC0, 0, 0, 0, 1);

    // ---- layer 0: CSR (tgt-sorted streams with fused weights) + aggregation ----
    hipMemsetAsync(cnt, 0, (size_t)(N1 + 1) * 4, stream);
    hist_k<<<(E0 + 255) / 256, 256, 0, stream>>>(ei0, E0, cnt);
    {
        int nb = (N1 + 255) / 256;
        scan1_k<<<nb, 256, 0, stream>>>(cnt, off, bsum, N1);
        scan2_k<<<1, 256, 0, stream>>>(bsum, nb, off + N1);
        scan3_k<<<nb, 256, 0, stream>>>(off, cursor, bsum, N1);
    }
    scatter0_k<<<(E0 + 255) / 256, 256, 0, stream>>>(ei0, et0, E0, cursor, ajn0, ain0, src_s, rt_s, w4_s);
    aggregate0_k<<<(N1 + 3) / 4, 256, 0, stream>>>(src_s, rt_s, w4_s, off, hj0, z0, N1);

    // ---- layer 0: chunked q/k/v (MFMA) + relation attention ----
    for (int c = 0; c < N1 / CHQ; ++c) {
        const unsigned short* zc = z0 + (long)c * CHQ * HC0;
        long sA = (long)N1 * HC0, sB = (long)HC0 * HC0, sC = (long)CHQ * HC0;
        gemm_mfma3_k<unsigned short><<<dim3(2, (CHQ + 127) / 128, 3 * R), 256, 0, stream>>>(
            zc, zc, zc, wqt0, wkt0, wvt0, qc, kc, vc, nullptr, nullptr, nullptr,
            dflag, CHQ, HC0, HC0, sA, sB, sC, R);
        fused_attn0_k<<<(CHQ + 3) / 4, 256, 0, stream>>>(qc, kc, vc, Wr0, x1, c * CHQ, CHQ, dflag);
    }

    // ---- layer 1: features + alpha (MFMA) ----
    gemm_mfma3_k<unsigned short><<<dim3(1, (N2 + 127) / 128, 3), 256, 0, stream>>>(
        x1, x1, x1, wjt1, wit1, swt1, hj1, hi1, self1, nullptr, nullptr, sb1,
        dflag, N2, C1, HC0, 0, 0, 0, 1);
    gemm_mfma3_k<float><<<dim3(1, (N2 + 127) / 128, 2), 256, 0, stream>>>(
        hj1, hi1, hi1, atA1j, atA1i, atA1i, ajn1, ain1, ain1, nullptr, nullptr, nullptr,
        dflag, N2, 5, C1, 0, 0, 0, 1);

    // ---- layer 1: CSR + aggregation ----
    hipMemsetAsync(cnt, 0, (size_t)(N2 + 1) * 4, stream);
    hist_k<<<(E1 + 255) / 256, 256, 0, stream>>>(ei1, E1, cnt);
    {
        int nb = (N2 + 255) / 256;
        scan1_k<<<nb, 256, 0, stream>>>(cnt, off, bsum, N2);
        scan2_k<<<1, 256, 0, stream>>>(bsum, nb, off + N2);
        scan3_k<<<nb, 256, 0, stream>>>(off, cursor, bsum, N2);
    }
    scatter1_k<<<(E1 + 255) / 256, 256, 0, stream>>>(ei1, et1, E1, cursor, ajn1, ain1, src_s, rt_s, w4_s);
    aggregate1_k<<<(N2 + 3) / 4, 256, 0, stream>>>(src_s, rt_s, w4_s, off, hj1, z1, N2);

    // ---- layer 1: q/k/v + attention + log_softmax ----
    {
        long sA = (long)N2 * C1, sB = (long)C1 * C1, sC = (long)N2 * C1;
        gemm_mfma3_k<unsigned short><<<dim3(1, (N2 + 127) / 128, 3 * R), 256, 0, stream>>>(
            z1, z1, z1, wqt1, wkt1, wvt1, q1b, k1b, v1b, nullptr, nullptr, nullptr,
            dflag, N2, C1, C1, sA, sB, sC, R);
    }
    fused_attn1_k<<<(N2 + 3) / 4, 256, 0, stream>>>(q1b, k1b, v1b, Wr1, self1, d_out, N2, dflag);
}